// Round 1
// baseline (7751.236 us; speedup 1.0000x reference)
//
#include <hip/hip_runtime.h>
#include <math.h>

// ---------------- constants ----------------
constexpr int Bsz = 4, T = 2048, D = 512, H = 8, Lnum = 6, DFF = 2048, DK = 64;
constexpr float SCALE = 0.08838834764831845f;   // 1/sqrt(128)
constexpr float INV15 = 1.0f / 1.5f;

__device__ __forceinline__ float wave_red_sum(float v) {
    for (int o = 32; o > 0; o >>= 1) v += __shfl_down(v, o, 64);
    return __shfl(v, 0, 64);
}

// ---------------- embed: h = where(pad, pad_tok, LN(xc*ip_w+ip_b)*g+b + 0.1*pos) ----------------
__global__ __launch_bounds__(64)
void embed_kernel(const float* __restrict__ x, const float* __restrict__ ip_w,
                  const float* __restrict__ ip_b, const float* __restrict__ g,
                  const float* __restrict__ bta, const float* __restrict__ pos,
                  const float* __restrict__ pad_tok, float* __restrict__ h)
{
    int row = blockIdx.x;           // b*T + t
    int t = row & (T - 1);
    int lane = threadIdx.x;
    float xv = x[row];
    float xc = fminf(fmaxf(xv, -10.f), 10.f);
    bool pad = (xc == -1.0f);
    float pre[8];
    float s = 0.f, s2 = 0.f;
#pragma unroll
    for (int j = 0; j < 8; j++) {
        int d = j * 64 + lane;
        float p = xc * ip_w[d] + ip_b[d];
        pre[j] = p; s += p; s2 += p * p;
    }
    s = wave_red_sum(s); s2 = wave_red_sum(s2);
    float m = s * (1.f / 512.f);
    float var = s2 * (1.f / 512.f) - m * m;
    float rstd = 1.f / sqrtf(var + 1e-5f);
#pragma unroll
    for (int j = 0; j < 8; j++) {
        int d = j * 64 + lane;
        float hv = (pre[j] - m) * rstd * g[d] + bta[d] + 0.1f * pos[(size_t)t * D + d];
        if (pad) hv = pad_tok[d];
        h[(size_t)row * D + d] = hv;
    }
}

// ---------------- row LayerNorm (D=512), one wave per row ----------------
__global__ __launch_bounds__(64)
void ln_kernel(const float* __restrict__ in, float* __restrict__ out,
               const float* __restrict__ g, const float* __restrict__ b)
{
    int row = blockIdx.x;
    int lane = threadIdx.x;
    const float* r = in + (size_t)row * D;
    float4 v0 = ((const float4*)r)[lane];
    float4 v1 = ((const float4*)r)[lane + 64];
    float s = v0.x + v0.y + v0.z + v0.w + v1.x + v1.y + v1.z + v1.w;
    float s2 = v0.x*v0.x + v0.y*v0.y + v0.z*v0.z + v0.w*v0.w
             + v1.x*v1.x + v1.y*v1.y + v1.z*v1.z + v1.w*v1.w;
    s = wave_red_sum(s); s2 = wave_red_sum(s2);
    float m = s * (1.f / 512.f);
    float var = s2 * (1.f / 512.f) - m * m;
    float rstd = 1.f / sqrtf(var + 1e-5f);
    float4 g0 = ((const float4*)g)[lane], g1 = ((const float4*)g)[lane + 64];
    float4 b0 = ((const float4*)b)[lane], b1 = ((const float4*)b)[lane + 64];
    float4 o0, o1;
    o0.x = (v0.x - m) * rstd * g0.x + b0.x; o0.y = (v0.y - m) * rstd * g0.y + b0.y;
    o0.z = (v0.z - m) * rstd * g0.z + b0.z; o0.w = (v0.w - m) * rstd * g0.w + b0.w;
    o1.x = (v1.x - m) * rstd * g1.x + b1.x; o1.y = (v1.y - m) * rstd * g1.y + b1.y;
    o1.z = (v1.z - m) * rstd * g1.z + b1.z; o1.w = (v1.w - m) * rstd * g1.w + b1.w;
    ((float4*)(out + (size_t)row * D))[lane] = o0;
    ((float4*)(out + (size_t)row * D))[lane + 64] = o1;
}

// ---------------- q/k head-chunk normalize: v / max(||v||,1e-8), one wave per 64-chunk ----------------
__global__ __launch_bounds__(256)
void qknorm_kernel(float* __restrict__ q, float* __restrict__ k)
{
    float* p = blockIdx.y ? k : q;
    int chunk = blockIdx.x * 4 + (threadIdx.x >> 6);
    int lane = threadIdx.x & 63;
    size_t idx = (size_t)chunk * 64 + lane;
    float v = p[idx];
    float s = wave_red_sum(v * v);
    float denom = fmaxf(sqrtf(s), 1e-8f);
    p[idx] = v / denom;
}

// ---------------- fp32 GEMM: C[M,N] = epilogue(A[M,K] @ B[K,N] + bias) ----------------
// EPI 0: v            1: res + gate*0.5*v      2: gelu_exact(v)      3: clip(res + gate*v, +-10)
template<int EPI>
__global__ __launch_bounds__(256)
void gemm_kernel(const float* __restrict__ A, const float* __restrict__ B,
                 const float* __restrict__ bias, const float* __restrict__ res,
                 float* __restrict__ C, int M, int N, int K,
                 const float* __restrict__ gate_p)
{
    __shared__ float As[16][68];
    __shared__ float Bs[16][68];
    const int tid = threadIdx.x;
    const int tx = tid & 15, ty = tid >> 4;
    const int m0 = blockIdx.y * 64, n0 = blockIdx.x * 64;
    const int la_m = tid >> 2;            // 0..63
    const int la_c = (tid & 3) * 4;       // 0,4,8,12
    const int lb_k = tid >> 4;            // 0..15
    const int lb_c = (tid & 15) * 4;      // 0..60
    const float* Aptr = A + (size_t)(m0 + la_m) * K + la_c;
    const float* Bptr = B + (size_t)lb_k * N + n0 + lb_c;
    float acc[4][4] = {};
    for (int k0 = 0; k0 < K; k0 += 16) {
        float4 a = *(const float4*)(Aptr + k0);
        float4 bv = *(const float4*)(Bptr + (size_t)k0 * N);
        __syncthreads();
        As[la_c + 0][la_m] = a.x; As[la_c + 1][la_m] = a.y;
        As[la_c + 2][la_m] = a.z; As[la_c + 3][la_m] = a.w;
        *(float4*)&Bs[lb_k][lb_c] = bv;
        __syncthreads();
#pragma unroll
        for (int kk = 0; kk < 16; kk++) {
            float4 av = *(const float4*)&As[kk][ty * 4];
            float4 bw = *(const float4*)&Bs[kk][tx * 4];
            acc[0][0] += av.x * bw.x; acc[0][1] += av.x * bw.y; acc[0][2] += av.x * bw.z; acc[0][3] += av.x * bw.w;
            acc[1][0] += av.y * bw.x; acc[1][1] += av.y * bw.y; acc[1][2] += av.y * bw.z; acc[1][3] += av.y * bw.w;
            acc[2][0] += av.z * bw.x; acc[2][1] += av.z * bw.y; acc[2][2] += av.z * bw.z; acc[2][3] += av.z * bw.w;
            acc[3][0] += av.w * bw.x; acc[3][1] += av.w * bw.y; acc[3][2] += av.w * bw.z; acc[3][3] += av.w * bw.w;
        }
    }
    const float gate = (EPI == 1 || EPI == 3) ? gate_p[0] : 0.f;
    float bb[4];
    *(float4*)bb = *(const float4*)(bias + n0 + tx * 4);
#pragma unroll
    for (int j = 0; j < 4; j++) {
        size_t off = (size_t)(m0 + ty * 4 + j) * N + n0 + tx * 4;
        float v[4];
#pragma unroll
        for (int i = 0; i < 4; i++) v[i] = acc[j][i] + bb[i];
        if (EPI == 1) {
            float r[4]; *(float4*)r = *(const float4*)(res + off);
#pragma unroll
            for (int i = 0; i < 4; i++) v[i] = r[i] + gate * 0.5f * v[i];
        } else if (EPI == 2) {
#pragma unroll
            for (int i = 0; i < 4; i++) v[i] = 0.5f * v[i] * (1.f + erff(v[i] * 0.70710678118654752f));
        } else if (EPI == 3) {
            float r[4]; *(float4*)r = *(const float4*)(res + off);
#pragma unroll
            for (int i = 0; i < 4; i++) v[i] = fminf(fmaxf(r[i] + gate * v[i], -10.f), 10.f);
        }
        *(float4*)(C + off) = *(float4*)v;
    }
}

// ---------------- flash attention (causal, no-max softmax since |s|<=0.0884) ----------------
__global__ __launch_bounds__(256)
void attn_kernel(const float* __restrict__ q, const float* __restrict__ k,
                 const float* __restrict__ v, float* __restrict__ o)
{
    __shared__ float Qs[64][68];   // [dk][t]
    __shared__ float KP[64][68];   // K as [dk][s], then P as [s][t]
    __shared__ float Vs[64][68];   // [s][dk]
    __shared__ float Lred[64][17];
    const int bh = blockIdx.y;
    const int b = bh >> 3, hh = bh & 7;
    const int qt = blockIdx.x;
    const int tid = threadIdx.x;
    const int tx = tid & 15, ty = tid >> 4;
    const int lr = tid >> 4;            // 0..15
    const int lcf = (tid & 15) * 4;     // 0..60

    const float* qg = q + ((size_t)(b * T + qt * 64)) * D + hh * 64;
#pragma unroll
    for (int it = 0; it < 4; it++) {
        int r = lr + 16 * it;
        float4 a = *(const float4*)(qg + (size_t)r * D + lcf);
        Qs[lcf + 0][r] = a.x; Qs[lcf + 1][r] = a.y; Qs[lcf + 2][r] = a.z; Qs[lcf + 3][r] = a.w;
    }

    float oacc[4][4] = {};
    float l_part[4] = {0.f, 0.f, 0.f, 0.f};

    for (int st = 0; st <= qt; st++) {
        __syncthreads();
        const float* kg = k + ((size_t)(b * T + st * 64)) * D + hh * 64;
        const float* vg = v + ((size_t)(b * T + st * 64)) * D + hh * 64;
#pragma unroll
        for (int it = 0; it < 4; it++) {
            int r = lr + 16 * it;
            float4 a = *(const float4*)(kg + (size_t)r * D + lcf);
            KP[lcf + 0][r] = a.x; KP[lcf + 1][r] = a.y; KP[lcf + 2][r] = a.z; KP[lcf + 3][r] = a.w;
            float4 vv = *(const float4*)(vg + (size_t)r * D + lcf);
            *(float4*)&Vs[r][lcf] = vv;
        }
        __syncthreads();
        float sacc[4][4] = {};
#pragma unroll 8
        for (int dk = 0; dk < 64; dk++) {
            float4 qv = *(const float4*)&Qs[dk][ty * 4];
            float4 kv = *(const float4*)&KP[dk][tx * 4];
            sacc[0][0] += qv.x * kv.x; sacc[0][1] += qv.x * kv.y; sacc[0][2] += qv.x * kv.z; sacc[0][3] += qv.x * kv.w;
            sacc[1][0] += qv.y * kv.x; sacc[1][1] += qv.y * kv.y; sacc[1][2] += qv.y * kv.z; sacc[1][3] += qv.y * kv.w;
            sacc[2][0] += qv.z * kv.x; sacc[2][1] += qv.z * kv.y; sacc[2][2] += qv.z * kv.z; sacc[2][3] += qv.z * kv.w;
            sacc[3][0] += qv.w * kv.x; sacc[3][1] += qv.w * kv.y; sacc[3][2] += qv.w * kv.z; sacc[3][3] += qv.w * kv.w;
        }
        __syncthreads();      // all K reads done; reuse KP for P
        const bool diag = (st == qt);
#pragma unroll
        for (int j = 0; j < 4; j++) {
#pragma unroll
            for (int i = 0; i < 4; i++) {
                float sc = fminf(fmaxf(sacc[j][i] * SCALE, -5.f), 5.f);
                float p;
                if (diag && (tx * 4 + i > ty * 4 + j)) p = 0.f;
                else p = expf(sc * INV15);
                KP[tx * 4 + i][ty * 4 + j] = p;
                l_part[j] += p;
            }
        }
        __syncthreads();
#pragma unroll 8
        for (int s = 0; s < 64; s++) {
            float4 pv = *(const float4*)&KP[s][ty * 4];
            float4 vv = *(const float4*)&Vs[s][tx * 4];
            oacc[0][0] += pv.x * vv.x; oacc[0][1] += pv.x * vv.y; oacc[0][2] += pv.x * vv.z; oacc[0][3] += pv.x * vv.w;
            oacc[1][0] += pv.y * vv.x; oacc[1][1] += pv.y * vv.y; oacc[1][2] += pv.y * vv.z; oacc[1][3] += pv.y * vv.w;
            oacc[2][0] += pv.z * vv.x; oacc[2][1] += pv.z * vv.y; oacc[2][2] += pv.z * vv.z; oacc[2][3] += pv.z * vv.w;
            oacc[3][0] += pv.w * vv.x; oacc[3][1] += pv.w * vv.y; oacc[3][2] += pv.w * vv.z; oacc[3][3] += pv.w * vv.w;
        }
    }
    __syncthreads();
#pragma unroll
    for (int j = 0; j < 4; j++) Lred[ty * 4 + j][tx] = l_part[j];
    __syncthreads();
    float* og = o + ((size_t)(b * T + qt * 64)) * D + hh * 64;
#pragma unroll
    for (int j = 0; j < 4; j++) {
        float lsum = 0.f;
#pragma unroll
        for (int c = 0; c < 16; c++) lsum += Lred[ty * 4 + j][c];
        float inv = 1.f / lsum;
        float4 ov;
        ov.x = oacc[j][0] * inv; ov.y = oacc[j][1] * inv;
        ov.z = oacc[j][2] * inv; ov.w = oacc[j][3] * inv;
        *(float4*)(og + (size_t)(ty * 4 + j) * D + tx * 4) = ov;
    }
}

// ---------------- masked-mean pool partials: part[b][chunk][513] ----------------
__global__ __launch_bounds__(256)
void pool_kernel(const float* __restrict__ hn, const float* __restrict__ x, float* __restrict__ part)
{
    int b = blockIdx.x, ch = blockIdx.y, tid = threadIdx.x;
    int t0 = ch * 128;
    float s0 = 0.f, s1 = 0.f, cnt = 0.f;
    for (int tt = 0; tt < 128; tt++) {
        int t = t0 + tt;
        float xv = x[b * T + t];
        float m = (xv == -1.0f) ? 0.f : 1.f;
        cnt += m;
        const float* r = hn + ((size_t)(b * T + t)) * D;
        s0 += r[tid] * m;
        s1 += r[tid + 256] * m;
    }
    float* pr = part + (size_t)(b * 16 + ch) * 513;
    pr[tid] = s0; pr[tid + 256] = s1;
    if (tid == 0) pr[512] = cnt;
}

// ---------------- heads: 3x (LN(mean) @ w + b), sigmoid on last ----------------
__global__ __launch_bounds__(64)
void head_kernel(const float* __restrict__ part,
                 const float* __restrict__ bh_g, const float* __restrict__ bh_bl,
                 const float* __restrict__ ah_g, const float* __restrict__ ah_bl,
                 const float* __restrict__ ch_g, const float* __restrict__ ch_bl,
                 const float* __restrict__ bh_w, const float* __restrict__ bh_b2,
                 const float* __restrict__ ah_w, const float* __restrict__ ah_b2,
                 const float* __restrict__ ch_w, const float* __restrict__ ch_b2,
                 float* __restrict__ out)
{
    int b = blockIdx.x, lane = threadIdx.x;
    float cnt = 0.f;
    for (int c = 0; c < 16; c++) cnt += part[(size_t)(b * 16 + c) * 513 + 512];
    float denom = fmaxf(cnt, 1.f);
    float md[8];
    float s = 0.f, s2 = 0.f;
#pragma unroll
    for (int j = 0; j < 8; j++) {
        int d = j * 64 + lane;
        float acc = 0.f;
        for (int c = 0; c < 16; c++) acc += part[(size_t)(b * 16 + c) * 513 + d];
        md[j] = acc / denom;
        s += md[j]; s2 += md[j] * md[j];
    }
    s = wave_red_sum(s); s2 = wave_red_sum(s2);
    float mu = s * (1.f / 512.f);
    float var = s2 * (1.f / 512.f) - mu * mu;
    float rstd = 1.f / sqrtf(var + 1e-5f);
    float a0 = 0.f, a1 = 0.f, a2 = 0.f, a3 = 0.f;
#pragma unroll
    for (int j = 0; j < 8; j++) {
        int d = j * 64 + lane;
        float z = (md[j] - mu) * rstd;
        float zb = z * bh_g[d] + bh_bl[d];
        a0 += zb * bh_w[d * 2 + 0];
        a1 += zb * bh_w[d * 2 + 1];
        a2 += (z * ah_g[d] + ah_bl[d]) * ah_w[d];
        a3 += (z * ch_g[d] + ch_bl[d]) * ch_w[d];
    }
    a0 = wave_red_sum(a0); a1 = wave_red_sum(a1);
    a2 = wave_red_sum(a2); a3 = wave_red_sum(a3);
    if (lane == 0) {
        out[b * 4 + 0] = a0 + bh_b2[0];
        out[b * 4 + 1] = a1 + bh_b2[1];
        out[b * 4 + 2] = a2 + ah_b2[0];
        float t3 = a3 + ch_b2[0];
        out[b * 4 + 3] = 1.f / (1.f + expf(-t3));
    }
}

// ---------------- launch ----------------
extern "C" void kernel_launch(void* const* d_in, const int* in_sizes, int n_in,
                              void* d_out, int out_size, void* d_ws, size_t ws_size,
                              hipStream_t stream)
{
    // dict order from setup_inputs()
    const float* x      = (const float*)d_in[0];
    const float* ip_w   = (const float*)d_in[1];
    const float* ip_b   = (const float*)d_in[2];
    const float* ip_ln_g= (const float*)d_in[3];
    const float* ip_ln_b= (const float*)d_in[4];
    const float* pos    = (const float*)d_in[5];
    const float* pad_tok= (const float*)d_in[6];
    const float* Wq = (const float*)d_in[7];  const float* bq = (const float*)d_in[8];
    const float* Wk = (const float*)d_in[9];  const float* bk = (const float*)d_in[10];
    const float* Wv = (const float*)d_in[11]; const float* bv = (const float*)d_in[12];
    const float* Wo = (const float*)d_in[13]; const float* bo = (const float*)d_in[14];
    const float* ln1_g = (const float*)d_in[15]; const float* ln1_b = (const float*)d_in[16];
    const float* ln2_g = (const float*)d_in[17]; const float* ln2_b = (const float*)d_in[18];
    const float* W1 = (const float*)d_in[19]; const float* b1 = (const float*)d_in[20];
    const float* W2 = (const float*)d_in[21]; const float* b2 = (const float*)d_in[22];
    const float* gate1 = (const float*)d_in[23]; const float* gate2 = (const float*)d_in[24];
    const float* fn_g = (const float*)d_in[25]; const float* fn_b = (const float*)d_in[26];
    // NOTE: dict order — all three ln_g/ln_b pairs BEFORE the w/b pairs
    const float* bh_g  = (const float*)d_in[27]; const float* bh_bl = (const float*)d_in[28];
    const float* ah_g  = (const float*)d_in[29]; const float* ah_bl = (const float*)d_in[30];
    const float* ch_g  = (const float*)d_in[31]; const float* ch_bl = (const float*)d_in[32];
    const float* bh_w  = (const float*)d_in[33]; const float* bh_b2 = (const float*)d_in[34];
    const float* ah_w  = (const float*)d_in[35]; const float* ah_b2 = (const float*)d_in[36];
    const float* ch_w  = (const float*)d_in[37]; const float* ch_b2 = (const float*)d_in[38];

    float* ws = (float*)d_ws;
    float* h    = ws;                   // 4,194,304 floats
    float* xn   = ws + 4194304;         // 4,194,304
    float* qb   = ws + 8388608;         // 4,194,304
    float* kb   = ws + 12582912;        // 4,194,304
    float* vb   = ws + 16777216;        // 4,194,304
    float* mid  = ws + 8388608;         // 16,777,216 (aliases q/k/v — dead by then)
    float* part = ws + 25165824;        // 4*16*513
    float* out  = (float*)d_out;

    embed_kernel<<<dim3(Bsz * T), dim3(64), 0, stream>>>(x, ip_w, ip_b, ip_ln_g, ip_ln_b, pos, pad_tok, h);

    for (int i = 0; i < Lnum; i++) {
        const size_t dd = (size_t)i * D * D;
        const size_t df = (size_t)i * D * DFF;
        ln_kernel<<<dim3(Bsz * T), dim3(64), 0, stream>>>(h, xn, ln1_g + i * D, ln1_b + i * D);
        gemm_kernel<0><<<dim3(8, 128), dim3(256), 0, stream>>>(xn, Wq + dd, bq + i * D, nullptr, qb, Bsz * T, D, D, nullptr);
        gemm_kernel<0><<<dim3(8, 128), dim3(256), 0, stream>>>(xn, Wk + dd, bk + i * D, nullptr, kb, Bsz * T, D, D, nullptr);
        gemm_kernel<0><<<dim3(8, 128), dim3(256), 0, stream>>>(xn, Wv + dd, bv + i * D, nullptr, vb, Bsz * T, D, D, nullptr);
        qknorm_kernel<<<dim3(16384, 2), dim3(256), 0, stream>>>(qb, kb);
        attn_kernel<<<dim3(32, 32), dim3(256), 0, stream>>>(qb, kb, vb, xn);
        gemm_kernel<1><<<dim3(8, 128), dim3(256), 0, stream>>>(xn, Wo + dd, bo + i * D, h, h, Bsz * T, D, D, gate1 + i);
        ln_kernel<<<dim3(Bsz * T), dim3(64), 0, stream>>>(h, xn, ln2_g + i * D, ln2_b + i * D);
        gemm_kernel<2><<<dim3(32, 128), dim3(256), 0, stream>>>(xn, W1 + df, b1 + i * DFF, nullptr, mid, Bsz * T, DFF, D, nullptr);
        gemm_kernel<3><<<dim3(8, 128), dim3(256), 0, stream>>>(mid, W2 + df, b2 + i * D, h, h, Bsz * T, D, DFF, gate2 + i);
    }

    ln_kernel<<<dim3(Bsz * T), dim3(64), 0, stream>>>(h, xn, fn_g, fn_b);
    pool_kernel<<<dim3(Bsz, 16), dim3(256), 0, stream>>>(xn, x, part);
    head_kernel<<<dim3(Bsz), dim3(64), 0, stream>>>(part, bh_g, bh_bl, ah_g, ah_bl, ch_g, ch_bl,
                                                    bh_w, bh_b2, ah_w, ah_b2, ch_w, ch_b2, out);
}

// Round 2
// 1950.960 us; speedup vs baseline: 3.9730x; 3.9730x over previous
//
#include <hip/hip_runtime.h>
#include <math.h>

// ---------------- constants ----------------
constexpr int Bsz = 4, T = 2048, D = 512, H = 8, Lnum = 6, DFF = 2048, DK = 64;
constexpr int QS = 1536;                        // fused qkv row stride
constexpr float SCALE = 0.08838834764831845f;   // 1/sqrt(128)
constexpr float INV15 = 1.0f / 1.5f;

typedef __attribute__((ext_vector_type(8))) short svec8;   // 8 bf16 (4 VGPRs)
typedef __attribute__((ext_vector_type(4))) float fvec4;   // 4 fp32 acc

__device__ __forceinline__ fvec4 mfma16(svec8 a, svec8 b, fvec4 c) {
    return __builtin_amdgcn_mfma_f32_16x16x32_bf16(a, b, c, 0, 0, 0);
}
__device__ __forceinline__ unsigned short f2b(float f) {
    unsigned int u = __float_as_uint(f);
    u += 0x7fffu + ((u >> 16) & 1u);
    return (unsigned short)(u >> 16);
}
__device__ __forceinline__ float b2f(unsigned short h) {
    return __uint_as_float(((unsigned int)h) << 16);
}
__device__ __forceinline__ float wave_red_sum(float v) {
    for (int o = 32; o > 0; o >>= 1) v += __shfl_down(v, o, 64);
    return __shfl(v, 0, 64);
}

// ---------------- embed (fp32 h) ----------------
__global__ __launch_bounds__(64)
void embed_kernel(const float* __restrict__ x, const float* __restrict__ ip_w,
                  const float* __restrict__ ip_b, const float* __restrict__ g,
                  const float* __restrict__ bta, const float* __restrict__ pos,
                  const float* __restrict__ pad_tok, float* __restrict__ h)
{
    int row = blockIdx.x;
    int t = row & (T - 1);
    int lane = threadIdx.x;
    float xv = x[row];
    float xc = fminf(fmaxf(xv, -10.f), 10.f);
    bool pad = (xc == -1.0f);
    float pre[8];
    float s = 0.f, s2 = 0.f;
#pragma unroll
    for (int j = 0; j < 8; j++) {
        int d = j * 64 + lane;
        float p = xc * ip_w[d] + ip_b[d];
        pre[j] = p; s += p; s2 += p * p;
    }
    s = wave_red_sum(s); s2 = wave_red_sum(s2);
    float m = s * (1.f / 512.f);
    float var = s2 * (1.f / 512.f) - m * m;
    float rstd = 1.f / sqrtf(var + 1e-5f);
#pragma unroll
    for (int j = 0; j < 8; j++) {
        int d = j * 64 + lane;
        float hv = (pre[j] - m) * rstd * g[d] + bta[d] + 0.1f * pos[(size_t)t * D + d];
        if (pad) hv = pad_tok[d];
        h[(size_t)row * D + d] = hv;
    }
}

// ---------------- LayerNorm fp32 -> fp32 (final) ----------------
__global__ __launch_bounds__(64)
void ln_kernel(const float* __restrict__ in, float* __restrict__ out,
               const float* __restrict__ g, const float* __restrict__ b)
{
    int row = blockIdx.x;
    int lane = threadIdx.x;
    const float* r = in + (size_t)row * D;
    float4 v0 = ((const float4*)r)[lane];
    float4 v1 = ((const float4*)r)[lane + 64];
    float s = v0.x + v0.y + v0.z + v0.w + v1.x + v1.y + v1.z + v1.w;
    float s2 = v0.x*v0.x + v0.y*v0.y + v0.z*v0.z + v0.w*v0.w
             + v1.x*v1.x + v1.y*v1.y + v1.z*v1.z + v1.w*v1.w;
    s = wave_red_sum(s); s2 = wave_red_sum(s2);
    float m = s * (1.f / 512.f);
    float var = s2 * (1.f / 512.f) - m * m;
    float rstd = 1.f / sqrtf(var + 1e-5f);
    float4 g0 = ((const float4*)g)[lane], g1 = ((const float4*)g)[lane + 64];
    float4 b0 = ((const float4*)b)[lane], b1 = ((const float4*)b)[lane + 64];
    float4 o0, o1;
    o0.x = (v0.x - m) * rstd * g0.x + b0.x; o0.y = (v0.y - m) * rstd * g0.y + b0.y;
    o0.z = (v0.z - m) * rstd * g0.z + b0.z; o0.w = (v0.w - m) * rstd * g0.w + b0.w;
    o1.x = (v1.x - m) * rstd * g1.x + b1.x; o1.y = (v1.y - m) * rstd * g1.y + b1.y;
    o1.z = (v1.z - m) * rstd * g1.z + b1.z; o1.w = (v1.w - m) * rstd * g1.w + b1.w;
    ((float4*)(out + (size_t)row * D))[lane] = o0;
    ((float4*)(out + (size_t)row * D))[lane + 64] = o1;
}

// ---------------- LayerNorm fp32 -> bf16 ----------------
__global__ __launch_bounds__(64)
void ln_bf16_kernel(const float* __restrict__ in, unsigned short* __restrict__ out,
                    const float* __restrict__ g, const float* __restrict__ b)
{
    int row = blockIdx.x;
    int lane = threadIdx.x;
    const float* r = in + (size_t)row * D;
    float4 v0 = ((const float4*)r)[lane];
    float4 v1 = ((const float4*)r)[lane + 64];
    float s = v0.x + v0.y + v0.z + v0.w + v1.x + v1.y + v1.z + v1.w;
    float s2 = v0.x*v0.x + v0.y*v0.y + v0.z*v0.z + v0.w*v0.w
             + v1.x*v1.x + v1.y*v1.y + v1.z*v1.z + v1.w*v1.w;
    s = wave_red_sum(s); s2 = wave_red_sum(s2);
    float m = s * (1.f / 512.f);
    float var = s2 * (1.f / 512.f) - m * m;
    float rstd = 1.f / sqrtf(var + 1e-5f);
    float4 g0 = ((const float4*)g)[lane], g1 = ((const float4*)g)[lane + 64];
    float4 b0 = ((const float4*)b)[lane], b1 = ((const float4*)b)[lane + 64];
    unsigned short o0[4], o1[4];
    o0[0] = f2b((v0.x - m) * rstd * g0.x + b0.x); o0[1] = f2b((v0.y - m) * rstd * g0.y + b0.y);
    o0[2] = f2b((v0.z - m) * rstd * g0.z + b0.z); o0[3] = f2b((v0.w - m) * rstd * g0.w + b0.w);
    o1[0] = f2b((v1.x - m) * rstd * g1.x + b1.x); o1[1] = f2b((v1.y - m) * rstd * g1.y + b1.y);
    o1[2] = f2b((v1.z - m) * rstd * g1.z + b1.z); o1[3] = f2b((v1.w - m) * rstd * g1.w + b1.w);
    *(uint2*)(out + (size_t)row * D + lane * 4) = *(uint2*)o0;
    *(uint2*)(out + (size_t)row * D + 256 + lane * 4) = *(uint2*)o1;
}

// ---------------- weight transpose + cast: fp32 [K][N] -> bf16 [N][K], per layer ----------------
__global__ __launch_bounds__(256)
void wconv_kernel(const float* __restrict__ wq, const float* __restrict__ wk,
                  const float* __restrict__ wv, const float* __restrict__ wo,
                  const float* __restrict__ w1, const float* __restrict__ w2,
                  unsigned short* __restrict__ oq, unsigned short* __restrict__ ok,
                  unsigned short* __restrict__ ov, unsigned short* __restrict__ oo,
                  unsigned short* __restrict__ o1, unsigned short* __restrict__ o2)
{
    __shared__ float tile[32][33];
    int bid = blockIdx.x;
    const float* in; unsigned short* out; int K, N, kt, nt;
    if (bid < 1024) {
        int sel = bid >> 8, loc = bid & 255;
        in  = sel == 0 ? wq : sel == 1 ? wk : sel == 2 ? wv : wo;
        out = sel == 0 ? oq : sel == 1 ? ok : sel == 2 ? ov : oo;
        K = 512; N = 512; kt = loc >> 4; nt = loc & 15;
    } else if (bid < 2048) {
        int loc = bid - 1024; in = w1; out = o1; K = 512; N = 2048; kt = loc >> 6; nt = loc & 63;
    } else {
        int loc = bid - 2048; in = w2; out = o2; K = 2048; N = 512; kt = loc >> 4; nt = loc & 15;
    }
    int k0 = kt * 32, n0 = nt * 32;
    int t = threadIdx.x;
    int kr = t >> 3, nc = (t & 7) * 4;
    float4 v = *(const float4*)(in + (size_t)(k0 + kr) * N + n0 + nc);
    tile[kr][nc] = v.x; tile[kr][nc + 1] = v.y; tile[kr][nc + 2] = v.z; tile[kr][nc + 3] = v.w;
    __syncthreads();
    unsigned short o[4];
#pragma unroll
    for (int i = 0; i < 4; i++) o[i] = f2b(tile[nc + i][kr]);
    *(uint2*)(out + (size_t)(n0 + kr) * K + k0 + nc) = *(uint2*)o;
}

// ---------------- q/k normalize in-place on bf16 ----------------
__global__ __launch_bounds__(256)
void qknorm_kernel(unsigned short* __restrict__ qkv)
{
    int chunk = blockIdx.x * 4 + (threadIdx.x >> 6);   // row*16 + cc, cc 0..15 covers q(8) then k(8)
    int lane = threadIdx.x & 63;
    int row = chunk >> 4, cc = chunk & 15;
    size_t idx = (size_t)row * QS + cc * 64 + lane;
    float v = b2f(qkv[idx]);
    float s = wave_red_sum(v * v);
    float denom = fmaxf(sqrtf(s), 1e-8f);
    qkv[idx] = f2b(v / denom);
}

// ---------------- bf16 MFMA GEMM: C[M,N] = epi(A[M,K] @ BT[N,K]^T + bias) ----------------
// EPI 0: qkv fused (OBF=1, segmented bias)   1: res + gate*0.5*v (fp32)
// EPI 2: gelu exact (OBF=1)                  3: clip(res + gate*v, +-10) (fp32)
template<int EPI, int OBF>
__global__ __launch_bounds__(256)
void gemm_bf16(const unsigned short* __restrict__ A, const unsigned short* __restrict__ BT,
               const float* __restrict__ bias, const float* __restrict__ bias_b,
               const float* __restrict__ bias_c, const float* __restrict__ res,
               void* __restrict__ Cv, int M, int N, int K, const float* __restrict__ gate_p)
{
    __shared__ __align__(16) unsigned short As[128][40];
    __shared__ __align__(16) unsigned short Bs[128][40];
    const int tid = threadIdx.x;
    const int wave = tid >> 6, lane = tid & 63, quad = lane >> 4, ln = lane & 15;
    const int wm = wave >> 1, wn = wave & 1;
    const int m0 = blockIdx.y * 128, n0 = blockIdx.x * 128;
    const int srow = tid >> 1, skg = (tid & 1) * 16;
    const unsigned short* Ag = A + (size_t)(m0 + srow) * K + skg;
    const unsigned short* Bg = BT + (size_t)(n0 + srow) * K + skg;

    fvec4 acc[4][4];
#pragma unroll
    for (int mt = 0; mt < 4; mt++)
#pragma unroll
        for (int nt = 0; nt < 4; nt++)
#pragma unroll
            for (int r = 0; r < 4; r++) acc[mt][nt][r] = 0.f;

    for (int k0 = 0; k0 < K; k0 += 32) {
        uint4 a0 = *(const uint4*)(Ag + k0);
        uint4 a1 = *(const uint4*)(Ag + k0 + 8);
        uint4 b0 = *(const uint4*)(Bg + k0);
        uint4 b1 = *(const uint4*)(Bg + k0 + 8);
        __syncthreads();
        *(uint4*)&As[srow][skg] = a0; *(uint4*)&As[srow][skg + 8] = a1;
        *(uint4*)&Bs[srow][skg] = b0; *(uint4*)&Bs[srow][skg + 8] = b1;
        __syncthreads();
        svec8 af[4], bfr[4];
#pragma unroll
        for (int mt = 0; mt < 4; mt++) af[mt] = *(const svec8*)&As[wm * 64 + mt * 16 + ln][quad * 8];
#pragma unroll
        for (int nt = 0; nt < 4; nt++) bfr[nt] = *(const svec8*)&Bs[wn * 64 + nt * 16 + ln][quad * 8];
#pragma unroll
        for (int mt = 0; mt < 4; mt++)
#pragma unroll
            for (int nt = 0; nt < 4; nt++)
                acc[mt][nt] = mfma16(af[mt], bfr[nt], acc[mt][nt]);
    }

    const float gate = (EPI == 1 || EPI == 3) ? gate_p[0] : 0.f;
#pragma unroll
    for (int nt = 0; nt < 4; nt++) {
        int n = n0 + wn * 64 + nt * 16 + ln;
        float bb;
        if (EPI == 0) {        // segmented qkv bias: n in [0,1536)
            int nseg = n >> 9;
            const float* bsel = nseg == 0 ? bias : (nseg == 1 ? bias_b : bias_c);
            bb = bsel[n - nseg * 512];
        } else {
            bb = bias[n];
        }
#pragma unroll
        for (int mt = 0; mt < 4; mt++) {
#pragma unroll
            for (int r = 0; r < 4; r++) {
                int m = m0 + wm * 64 + mt * 16 + quad * 4 + r;
                size_t off = (size_t)m * N + n;
                float v = acc[mt][nt][r] + bb;
                if (EPI == 1) v = res[off] + gate * 0.5f * v;
                else if (EPI == 2) v = 0.5f * v * (1.f + erff(v * 0.70710678118654752f));
                else if (EPI == 3) v = fminf(fmaxf(res[off] + gate * v, -10.f), 10.f);
                if (OBF) ((unsigned short*)Cv)[off] = f2b(v);
                else ((float*)Cv)[off] = v;
            }
        }
    }
}

// ---------------- bf16 MFMA flash attention (causal, no-max softmax: |s|<=0.0884) ----------------
__global__ __launch_bounds__(256)
void attn_bf16_kernel(const unsigned short* __restrict__ qkv, unsigned short* __restrict__ o)
{
    __shared__ __align__(16) unsigned short Qs[64][72];
    __shared__ __align__(16) unsigned short Ks[64][72];
    __shared__ __align__(16) unsigned short Vt[64][72];   // transposed: [dk][s]
    __shared__ __align__(16) unsigned short Ps[64][72];
    const int bh = blockIdx.y, b = bh >> 3, hh = bh & 7;
    const int qt = blockIdx.x;
    const int tid = threadIdx.x, w = tid >> 6, lane = tid & 63, quad = lane >> 4, ln = lane & 15;
    const int srow = tid >> 2, skg = (tid & 3) * 16;

    // stage Q tile [64 q][64 dk]
    {
        const unsigned short* qg = qkv + (size_t)(b * T + qt * 64 + srow) * QS + hh * 64 + skg;
        uint4 q0 = *(const uint4*)qg; uint4 q1 = *(const uint4*)(qg + 8);
        *(uint4*)&Qs[srow][skg] = q0; *(uint4*)&Qs[srow][skg + 8] = q1;
    }

    fvec4 oacc[4];
#pragma unroll
    for (int nt = 0; nt < 4; nt++)
#pragma unroll
        for (int r = 0; r < 4; r++) oacc[nt][r] = 0.f;
    float l_part[4] = {0.f, 0.f, 0.f, 0.f};

    for (int st = 0; st <= qt; st++) {
        const unsigned short* kg = qkv + (size_t)(b * T + st * 64 + srow) * QS + 512 + hh * 64 + skg;
        const unsigned short* vg = qkv + (size_t)(b * T + st * 64 + srow) * QS + 1024 + hh * 64 + skg;
        uint4 k0v = *(const uint4*)kg; uint4 k1v = *(const uint4*)(kg + 8);
        uint4 v0v = *(const uint4*)vg; uint4 v1v = *(const uint4*)(vg + 8);
        __syncthreads();          // prev iter's MFMA reads of Ks/Vt done
        *(uint4*)&Ks[srow][skg] = k0v; *(uint4*)&Ks[srow][skg + 8] = k1v;
        unsigned short vtmp[16];
        *(uint4*)vtmp = v0v; *(uint4*)(vtmp + 8) = v1v;
#pragma unroll
        for (int i = 0; i < 16; i++) Vt[skg + i][srow] = vtmp[i];
        __syncthreads();

        // S = Q K^T  (wave w: q rows w*16..w*16+15, all 64 s)
        svec8 a0 = *(const svec8*)&Qs[w * 16 + ln][quad * 8];
        svec8 a1 = *(const svec8*)&Qs[w * 16 + ln][32 + quad * 8];
        fvec4 s[4];
#pragma unroll
        for (int nt = 0; nt < 4; nt++) {
#pragma unroll
            for (int r = 0; r < 4; r++) s[nt][r] = 0.f;
            svec8 bk0 = *(const svec8*)&Ks[nt * 16 + ln][quad * 8];
            svec8 bk1 = *(const svec8*)&Ks[nt * 16 + ln][32 + quad * 8];
            s[nt] = mfma16(a0, bk0, s[nt]);
            s[nt] = mfma16(a1, bk1, s[nt]);
        }

        // P = exp(clip(S*SCALE)/1.5), causal mask; write to Ps (wave-local rows)
        const int qg0 = qt * 64 + w * 16 + quad * 4;
#pragma unroll
        for (int nt = 0; nt < 4; nt++) {
            int scol = st * 64 + nt * 16 + ln;
#pragma unroll
            for (int r = 0; r < 4; r++) {
                float sc = fminf(fmaxf(s[nt][r] * SCALE, -5.f), 5.f);
                float p = (scol > qg0 + r) ? 0.f : expf(sc * INV15);
                l_part[r] += p;
                Ps[w * 16 + quad * 4 + r][nt * 16 + ln] = f2b(p);
            }
        }

        // O += P V   (Ps rows are wave-local; Vt covered by barrier above)
#pragma unroll
        for (int ks = 0; ks < 2; ks++) {
            svec8 pa = *(const svec8*)&Ps[w * 16 + ln][ks * 32 + quad * 8];
#pragma unroll
            for (int nt = 0; nt < 4; nt++) {
                svec8 vb = *(const svec8*)&Vt[nt * 16 + ln][ks * 32 + quad * 8];
                oacc[nt] = mfma16(pa, vb, oacc[nt]);
            }
        }
    }

    // reduce l across the 16 lanes of each quad, then write O (bf16)
#pragma unroll
    for (int r = 0; r < 4; r++) {
        float t = l_part[r];
        t += __shfl_xor(t, 1); t += __shfl_xor(t, 2);
        t += __shfl_xor(t, 4); t += __shfl_xor(t, 8);
        l_part[r] = t;
    }
    unsigned short* og = o + (size_t)(b * T + qt * 64 + w * 16 + quad * 4) * D + hh * 64;
#pragma unroll
    for (int r = 0; r < 4; r++) {
        float inv = 1.f / l_part[r];
#pragma unroll
        for (int nt = 0; nt < 4; nt++)
            og[(size_t)r * D + nt * 16 + ln] = f2b(oacc[nt][r] * inv);
    }
}

// ---------------- masked-mean pool partials ----------------
__global__ __launch_bounds__(256)
void pool_kernel(const float* __restrict__ hn, const float* __restrict__ x, float* __restrict__ part)
{
    int b = blockIdx.x, ch = blockIdx.y, tid = threadIdx.x;
    int t0 = ch * 128;
    float s0 = 0.f, s1 = 0.f, cnt = 0.f;
    for (int tt = 0; tt < 128; tt++) {
        int t = t0 + tt;
        float xv = x[b * T + t];
        float m = (xv == -1.0f) ? 0.f : 1.f;
        cnt += m;
        const float* r = hn + ((size_t)(b * T + t)) * D;
        s0 += r[tid] * m;
        s1 += r[tid + 256] * m;
    }
    float* pr = part + (size_t)(b * 16 + ch) * 513;
    pr[tid] = s0; pr[tid + 256] = s1;
    if (tid == 0) pr[512] = cnt;
}

// ---------------- heads ----------------
__global__ __launch_bounds__(64)
void head_kernel(const float* __restrict__ part,
                 const float* __restrict__ bh_g, const float* __restrict__ bh_bl,
                 const float* __restrict__ ah_g, const float* __restrict__ ah_bl,
                 const float* __restrict__ ch_g, const float* __restrict__ ch_bl,
                 const float* __restrict__ bh_w, const float* __restrict__ bh_b2,
                 const float* __restrict__ ah_w, const float* __restrict__ ah_b2,
                 const float* __restrict__ ch_w, const float* __restrict__ ch_b2,
                 float* __restrict__ out)
{
    int b = blockIdx.x, lane = threadIdx.x;
    float cnt = 0.f;
    for (int c = 0; c < 16; c++) cnt += part[(size_t)(b * 16 + c) * 513 + 512];
    float denom = fmaxf(cnt, 1.f);
    float md[8];
    float s = 0.f, s2 = 0.f;
#pragma unroll
    for (int j = 0; j < 8; j++) {
        int d = j * 64 + lane;
        float acc = 0.f;
        for (int c = 0; c < 16; c++) acc += part[(size_t)(b * 16 + c) * 513 + d];
        md[j] = acc / denom;
        s += md[j]; s2 += md[j] * md[j];
    }
    s = wave_red_sum(s); s2 = wave_red_sum(s2);
    float mu = s * (1.f / 512.f);
    float var = s2 * (1.f / 512.f) - mu * mu;
    float rstd = 1.f / sqrtf(var + 1e-5f);
    float a0 = 0.f, a1 = 0.f, a2 = 0.f, a3 = 0.f;
#pragma unroll
    for (int j = 0; j < 8; j++) {
        int d = j * 64 + lane;
        float z = (md[j] - mu) * rstd;
        float zb = z * bh_g[d] + bh_bl[d];
        a0 += zb * bh_w[d * 2 + 0];
        a1 += zb * bh_w[d * 2 + 1];
        a2 += (z * ah_g[d] + ah_bl[d]) * ah_w[d];
        a3 += (z * ch_g[d] + ch_bl[d]) * ch_w[d];
    }
    a0 = wave_red_sum(a0); a1 = wave_red_sum(a1);
    a2 = wave_red_sum(a2); a3 = wave_red_sum(a3);
    if (lane == 0) {
        out[b * 4 + 0] = a0 + bh_b2[0];
        out[b * 4 + 1] = a1 + bh_b2[1];
        out[b * 4 + 2] = a2 + ah_b2[0];
        float t3 = a3 + ch_b2[0];
        out[b * 4 + 3] = 1.f / (1.f + expf(-t3));
    }
}

// ---------------- launch ----------------
extern "C" void kernel_launch(void* const* d_in, const int* in_sizes, int n_in,
                              void* d_out, int out_size, void* d_ws, size_t ws_size,
                              hipStream_t stream)
{
    const float* x      = (const float*)d_in[0];
    const float* ip_w   = (const float*)d_in[1];
    const float* ip_b   = (const float*)d_in[2];
    const float* ip_ln_g= (const float*)d_in[3];
    const float* ip_ln_b= (const float*)d_in[4];
    const float* pos    = (const float*)d_in[5];
    const float* pad_tok= (const float*)d_in[6];
    const float* Wq = (const float*)d_in[7];  const float* bq = (const float*)d_in[8];
    const float* Wk = (const float*)d_in[9];  const float* bk = (const float*)d_in[10];
    const float* Wv = (const float*)d_in[11]; const float* bv = (const float*)d_in[12];
    const float* Wo = (const float*)d_in[13]; const float* bo = (const float*)d_in[14];
    const float* ln1_g = (const float*)d_in[15]; const float* ln1_b = (const float*)d_in[16];
    const float* ln2_g = (const float*)d_in[17]; const float* ln2_b = (const float*)d_in[18];
    const float* W1 = (const float*)d_in[19]; const float* b1 = (const float*)d_in[20];
    const float* W2 = (const float*)d_in[21]; const float* b2 = (const float*)d_in[22];
    const float* gate1 = (const float*)d_in[23]; const float* gate2 = (const float*)d_in[24];
    const float* fn_g = (const float*)d_in[25]; const float* fn_b = (const float*)d_in[26];
    const float* bh_g  = (const float*)d_in[27]; const float* bh_bl = (const float*)d_in[28];
    const float* ah_g  = (const float*)d_in[29]; const float* ah_bl = (const float*)d_in[30];
    const float* ch_g  = (const float*)d_in[31]; const float* ch_bl = (const float*)d_in[32];
    const float* bh_w  = (const float*)d_in[33]; const float* bh_b2 = (const float*)d_in[34];
    const float* ah_w  = (const float*)d_in[35]; const float* ah_b2 = (const float*)d_in[36];
    const float* ch_w  = (const float*)d_in[37]; const float* ch_b2 = (const float*)d_in[38];

    char* ws = (char*)d_ws;
    float*          h     = (float*)ws;                       // 16 MB fp32 [8192][512]
    unsigned short* act_b = (unsigned short*)(ws + 16777216); // 8 MB bf16 [8192][512] (xn / attn-out)
    unsigned short* qkv   = (unsigned short*)(ws + 25165824); // 24 MB bf16 [8192][1536]
    unsigned short* mid_b = (unsigned short*)(ws + 50331648); // 32 MB bf16 [8192][2048]
    float*          xn_f  = (float*)(ws + 50331648);          // 16 MB alias (final LN only)
    unsigned short* wT    = (unsigned short*)(ws + 83886080); // 6 MB per-layer transposed weights
    float*          part  = (float*)(ws + 90177536);
    float*          out   = (float*)d_out;

    unsigned short* wqT = wT;             // [512][512] x3 contiguous => [1536][512]
    unsigned short* wkT = wT + 262144;
    unsigned short* wvT = wT + 524288;
    unsigned short* woT = wT + 786432;
    unsigned short* w1T = wT + 1048576;   // [2048][512]
    unsigned short* w2T = wT + 2097152;   // [512][2048]

    embed_kernel<<<dim3(Bsz * T), dim3(64), 0, stream>>>(x, ip_w, ip_b, ip_ln_g, ip_ln_b, pos, pad_tok, h);

    for (int i = 0; i < Lnum; i++) {
        const size_t dd = (size_t)i * D * D;
        const size_t df = (size_t)i * D * DFF;
        wconv_kernel<<<dim3(3072), dim3(256), 0, stream>>>(Wq + dd, Wk + dd, Wv + dd, Wo + dd,
                                                           W1 + df, W2 + df,
                                                           wqT, wkT, wvT, woT, w1T, w2T);
        ln_bf16_kernel<<<dim3(Bsz * T), dim3(64), 0, stream>>>(h, act_b, ln1_g + i * D, ln1_b + i * D);
        // fused QKV: [8192,512] @ [512,1536] -> qkv bf16
        gemm_bf16<0, 1><<<dim3(12, 64), dim3(256), 0, stream>>>(act_b, wqT, bq + i * D, bk + i * D, bv + i * D,
                                                                nullptr, qkv, Bsz * T, QS, D, nullptr);
        qknorm_kernel<<<dim3(32768), dim3(256), 0, stream>>>(qkv);
        attn_bf16_kernel<<<dim3(32, 32), dim3(256), 0, stream>>>(qkv, act_b);
        gemm_bf16<1, 0><<<dim3(4, 64), dim3(256), 0, stream>>>(act_b, woT, bo + i * D, nullptr, nullptr,
                                                               h, h, Bsz * T, D, D, gate1 + i);
        ln_bf16_kernel<<<dim3(Bsz * T), dim3(64), 0, stream>>>(h, act_b, ln2_g + i * D, ln2_b + i * D);
        gemm_bf16<2, 1><<<dim3(16, 64), dim3(256), 0, stream>>>(act_b, w1T, b1 + i * DFF, nullptr, nullptr,
                                                                nullptr, mid_b, Bsz * T, DFF, D, nullptr);
        gemm_bf16<3, 0><<<dim3(4, 64), dim3(256), 0, stream>>>(mid_b, w2T, b2 + i * D, nullptr, nullptr,
                                                               h, h, Bsz * T, D, DFF, gate2 + i);
    }

    ln_kernel<<<dim3(Bsz * T), dim3(64), 0, stream>>>(h, xn_f, fn_g, fn_b);
    pool_kernel<<<dim3(Bsz, 16), dim3(256), 0, stream>>>(xn_f, x, part);
    head_kernel<<<dim3(Bsz), dim3(64), 0, stream>>>(part, bh_g, bh_bl, ah_g, ah_bl, ch_g, ch_bl,
                                                    bh_w, bh_b2, ah_w, ah_b2, ch_w, ch_b2, out);
}

// Round 3
// 1315.926 us; speedup vs baseline: 5.8903x; 1.4826x over previous
//
#include <hip/hip_runtime.h>
#include <math.h>

// ---------------- constants ----------------
constexpr int Bsz = 4, T = 2048, D = 512, H = 8, Lnum = 6, DFF = 2048, DK = 64;
constexpr int QS = 1536;                        // fused qkv row stride
constexpr float SCALE = 0.08838834764831845f;   // 1/sqrt(128)
// exp(s*SCALE/1.5) == exp2(s * C1); clip(+-5) provably no-op (|s|<=~1.01)
constexpr float C1 = 0.08838834764831845f * (1.4426950408889634f / 1.5f);

typedef __attribute__((ext_vector_type(8))) short svec8;   // 8 bf16 (4 VGPRs)
typedef __attribute__((ext_vector_type(4))) float fvec4;   // 4 fp32 acc

__device__ __forceinline__ fvec4 mfma16(svec8 a, svec8 b, fvec4 c) {
    return __builtin_amdgcn_mfma_f32_16x16x32_bf16(a, b, c, 0, 0, 0);
}
__device__ __forceinline__ unsigned short f2b(float f) {
    unsigned int u = __float_as_uint(f);
    u += 0x7fffu + ((u >> 16) & 1u);
    return (unsigned short)(u >> 16);
}
__device__ __forceinline__ float wave_red_sum(float v) {
    for (int o = 32; o > 0; o >>= 1) v += __shfl_down(v, o, 64);
    return __shfl(v, 0, 64);
}
// async global->LDS, 16B per lane; lds base must be wave-uniform (HW adds lane*16)
__device__ __forceinline__ void glds16(const unsigned short* g, unsigned short* l) {
    __builtin_amdgcn_global_load_lds(
        (const __attribute__((address_space(1))) unsigned int*)g,
        (__attribute__((address_space(3))) unsigned int*)l, 16, 0, 0);
}

// ---------------- embed (fp32 h) ----------------
__global__ __launch_bounds__(64)
void embed_kernel(const float* __restrict__ x, const float* __restrict__ ip_w,
                  const float* __restrict__ ip_b, const float* __restrict__ g,
                  const float* __restrict__ bta, const float* __restrict__ pos,
                  const float* __restrict__ pad_tok, float* __restrict__ h)
{
    int row = blockIdx.x;
    int t = row & (T - 1);
    int lane = threadIdx.x;
    float xv = x[row];
    float xc = fminf(fmaxf(xv, -10.f), 10.f);
    bool pad = (xc == -1.0f);
    float pre[8];
    float s = 0.f, s2 = 0.f;
#pragma unroll
    for (int j = 0; j < 8; j++) {
        int d = j * 64 + lane;
        float p = xc * ip_w[d] + ip_b[d];
        pre[j] = p; s += p; s2 += p * p;
    }
    s = wave_red_sum(s); s2 = wave_red_sum(s2);
    float m = s * (1.f / 512.f);
    float var = s2 * (1.f / 512.f) - m * m;
    float rstd = 1.f / sqrtf(var + 1e-5f);
#pragma unroll
    for (int j = 0; j < 8; j++) {
        int d = j * 64 + lane;
        float hv = (pre[j] - m) * rstd * g[d] + bta[d] + 0.1f * pos[(size_t)t * D + d];
        if (pad) hv = pad_tok[d];
        h[(size_t)row * D + d] = hv;
    }
}

// ---------------- LayerNorm fp32 -> fp32 (final) ----------------
__global__ __launch_bounds__(64)
void ln_kernel(const float* __restrict__ in, float* __restrict__ out,
               const float* __restrict__ g, const float* __restrict__ b)
{
    int row = blockIdx.x;
    int lane = threadIdx.x;
    const float* r = in + (size_t)row * D;
    float4 v0 = ((const float4*)r)[lane];
    float4 v1 = ((const float4*)r)[lane + 64];
    float s = v0.x + v0.y + v0.z + v0.w + v1.x + v1.y + v1.z + v1.w;
    float s2 = v0.x*v0.x + v0.y*v0.y + v0.z*v0.z + v0.w*v0.w
             + v1.x*v1.x + v1.y*v1.y + v1.z*v1.z + v1.w*v1.w;
    s = wave_red_sum(s); s2 = wave_red_sum(s2);
    float m = s * (1.f / 512.f);
    float var = s2 * (1.f / 512.f) - m * m;
    float rstd = 1.f / sqrtf(var + 1e-5f);
    float4 g0 = ((const float4*)g)[lane], g1 = ((const float4*)g)[lane + 64];
    float4 b0 = ((const float4*)b)[lane], b1 = ((const float4*)b)[lane + 64];
    float4 o0, o1;
    o0.x = (v0.x - m) * rstd * g0.x + b0.x; o0.y = (v0.y - m) * rstd * g0.y + b0.y;
    o0.z = (v0.z - m) * rstd * g0.z + b0.z; o0.w = (v0.w - m) * rstd * g0.w + b0.w;
    o1.x = (v1.x - m) * rstd * g1.x + b1.x; o1.y = (v1.y - m) * rstd * g1.y + b1.y;
    o1.z = (v1.z - m) * rstd * g1.z + b1.z; o1.w = (v1.w - m) * rstd * g1.w + b1.w;
    ((float4*)(out + (size_t)row * D))[lane] = o0;
    ((float4*)(out + (size_t)row * D))[lane + 64] = o1;
}

// ---------------- LayerNorm fp32 -> bf16 ----------------
__global__ __launch_bounds__(64)
void ln_bf16_kernel(const float* __restrict__ in, unsigned short* __restrict__ out,
                    const float* __restrict__ g, const float* __restrict__ b)
{
    int row = blockIdx.x;
    int lane = threadIdx.x;
    const float* r = in + (size_t)row * D;
    float4 v0 = ((const float4*)r)[lane];
    float4 v1 = ((const float4*)r)[lane + 64];
    float s = v0.x + v0.y + v0.z + v0.w + v1.x + v1.y + v1.z + v1.w;
    float s2 = v0.x*v0.x + v0.y*v0.y + v0.z*v0.z + v0.w*v0.w
             + v1.x*v1.x + v1.y*v1.y + v1.z*v1.z + v1.w*v1.w;
    s = wave_red_sum(s); s2 = wave_red_sum(s2);
    float m = s * (1.f / 512.f);
    float var = s2 * (1.f / 512.f) - m * m;
    float rstd = 1.f / sqrtf(var + 1e-5f);
    float4 g0 = ((const float4*)g)[lane], g1 = ((const float4*)g)[lane + 64];
    float4 b0 = ((const float4*)b)[lane], b1 = ((const float4*)b)[lane + 64];
    unsigned short o0[4], o1[4];
    o0[0] = f2b((v0.x - m) * rstd * g0.x + b0.x); o0[1] = f2b((v0.y - m) * rstd * g0.y + b0.y);
    o0[2] = f2b((v0.z - m) * rstd * g0.z + b0.z); o0[3] = f2b((v0.w - m) * rstd * g0.w + b0.w);
    o1[0] = f2b((v1.x - m) * rstd * g1.x + b1.x); o1[1] = f2b((v1.y - m) * rstd * g1.y + b1.y);
    o1[2] = f2b((v1.z - m) * rstd * g1.z + b1.z); o1[3] = f2b((v1.w - m) * rstd * g1.w + b1.w);
    *(uint2*)(out + (size_t)row * D + lane * 4) = *(uint2*)o0;
    *(uint2*)(out + (size_t)row * D + 256 + lane * 4) = *(uint2*)o1;
}

// ---------------- weight transpose + cast: fp32 [K][N] -> bf16 [N][K], per layer ----------------
__global__ __launch_bounds__(256)
void wconv_kernel(const float* __restrict__ wq, const float* __restrict__ wk,
                  const float* __restrict__ wv, const float* __restrict__ wo,
                  const float* __restrict__ w1, const float* __restrict__ w2,
                  unsigned short* __restrict__ oq, unsigned short* __restrict__ ok,
                  unsigned short* __restrict__ ov, unsigned short* __restrict__ oo,
                  unsigned short* __restrict__ o1, unsigned short* __restrict__ o2)
{
    __shared__ float tile[32][33];
    int bid = blockIdx.x;
    const float* in; unsigned short* out; int K, N, kt, nt;
    if (bid < 1024) {
        int sel = bid >> 8, loc = bid & 255;
        in  = sel == 0 ? wq : sel == 1 ? wk : sel == 2 ? wv : wo;
        out = sel == 0 ? oq : sel == 1 ? ok : sel == 2 ? ov : oo;
        K = 512; N = 512; kt = loc >> 4; nt = loc & 15;
    } else if (bid < 2048) {
        int loc = bid - 1024; in = w1; out = o1; K = 512; N = 2048; kt = loc >> 6; nt = loc & 63;
    } else {
        int loc = bid - 2048; in = w2; out = o2; K = 2048; N = 512; kt = loc >> 4; nt = loc & 15;
    }
    int k0 = kt * 32, n0 = nt * 32;
    int t = threadIdx.x;
    int kr = t >> 3, nc = (t & 7) * 4;
    float4 v = *(const float4*)(in + (size_t)(k0 + kr) * N + n0 + nc);
    tile[kr][nc] = v.x; tile[kr][nc + 1] = v.y; tile[kr][nc + 2] = v.z; tile[kr][nc + 3] = v.w;
    __syncthreads();
    unsigned short o[4];
#pragma unroll
    for (int i = 0; i < 4; i++) o[i] = f2b(tile[nc + i][kr]);
    *(uint2*)(out + (size_t)(n0 + kr) * K + k0 + nc) = *(uint2*)o;
}

// ---------------- V transpose: qkv v-seg -> vt[bh][dk][T] bf16 ----------------
__global__ __launch_bounds__(256)
void vtrans_kernel(const unsigned short* __restrict__ qkv, unsigned short* __restrict__ vt)
{
    __shared__ __align__(16) unsigned short Tl[64][72];
    const int t0 = blockIdx.x * 64, bh = blockIdx.y, b = bh >> 3, hh = bh & 7;
    const int tid = threadIdx.x;
    const int r = tid >> 2, c = (tid & 3) * 16;
    const unsigned short* src = qkv + (size_t)(b * T + t0 + r) * QS + 1024 + hh * 64 + c;
    uint4 a0 = *(const uint4*)src, a1 = *(const uint4*)(src + 8);
    *(uint4*)&Tl[r][c] = a0; *(uint4*)&Tl[r][c + 8] = a1;
    __syncthreads();
    unsigned short tmp[16];
#pragma unroll
    for (int i = 0; i < 16; i++) tmp[i] = Tl[c + i][r];    // r is dk here, c is t-chunk
    unsigned short* dst = vt + (size_t)(bh * 64 + r) * T + t0 + c;
    *(uint4*)dst = *(uint4*)tmp; *(uint4*)(dst + 8) = *(uint4*)(tmp + 8);
}

// ---------------- bf16 MFMA GEMM, global_load_lds + BK=64 XOR swizzle ----------------
// EPI 0: qkv fused (OBF=1, segmented bias, fused q/k L2-normalize)
// EPI 1: res + gate*0.5*v (fp32 out)   EPI 2: gelu exact (OBF=1)   EPI 3: clip(res+gate*v,+-10) (fp32 out)
template<int EPI, int OBF, int BM>
__global__ __launch_bounds__(256)
void gemm_bf16(const unsigned short* __restrict__ A, const unsigned short* __restrict__ BT,
               const float* __restrict__ bias, const float* __restrict__ bias_b,
               const float* __restrict__ bias_c, const float* __restrict__ res,
               void* __restrict__ Cv, int M, int N, int K, const float* __restrict__ gate_p)
{
    constexpr int WN = (BM == 128) ? 2 : 4;   // waves along n
    constexpr int WSPAN = 128 / WN;           // n-span per wave (64 or 32)
    constexpr int NT = WSPAN / 16;            // 4 or 2
    constexpr int MT = 4;
    constexpr int ACALLS = BM / 32;
    __shared__ __align__(16) unsigned short As[BM * 64];
    __shared__ __align__(16) unsigned short Bs[128 * 64];
    const int tid = threadIdx.x, w = tid >> 6, lane = tid & 63, quad = lane >> 4, ln = lane & 15;
    const int wm = w / WN, wn = w % WN;
    const int m0 = blockIdx.y * BM, n0 = blockIdx.x * 128;
    // swizzled staging: lane stores global chunk jg at LDS position (row*8 + (jg^ (row&7)))
    const int jg = (lane & 7) ^ ((lane >> 3) & 7);
    const int rb = w * 8 + (lane >> 3);
    const unsigned short* Agl = A + (size_t)(m0 + rb) * K + jg * 8;
    const unsigned short* Bgl = BT + (size_t)(n0 + rb) * K + jg * 8;

    fvec4 acc[MT][NT];
#pragma unroll
    for (int mt = 0; mt < MT; mt++)
#pragma unroll
        for (int nt = 0; nt < NT; nt++)
#pragma unroll
            for (int r = 0; r < 4; r++) acc[mt][nt][r] = 0.f;

    for (int k0 = 0; k0 < K; k0 += 64) {
        __syncthreads();
#pragma unroll
        for (int c = 0; c < ACALLS; c++)
            glds16(Agl + k0 + (size_t)c * 32 * K, As + c * 2048 + w * 512);
#pragma unroll
        for (int c = 0; c < 4; c++)
            glds16(Bgl + k0 + (size_t)c * 32 * K, Bs + c * 2048 + w * 512);
        __syncthreads();
#pragma unroll
        for (int kk = 0; kk < 2; kk++) {
            svec8 af[MT], bfr[NT];
#pragma unroll
            for (int mt = 0; mt < MT; mt++) {
                int row = wm * 64 + mt * 16 + ln;
                af[mt] = *(const svec8*)(As + (((row << 3) + ((kk * 4 + quad) ^ (row & 7))) << 3));
            }
#pragma unroll
            for (int nt = 0; nt < NT; nt++) {
                int row = wn * WSPAN + nt * 16 + ln;
                bfr[nt] = *(const svec8*)(Bs + (((row << 3) + ((kk * 4 + quad) ^ (row & 7))) << 3));
            }
#pragma unroll
            for (int mt = 0; mt < MT; mt++)
#pragma unroll
                for (int nt = 0; nt < NT; nt++)
                    acc[mt][nt] = mfma16(af[mt], bfr[nt], acc[mt][nt]);
        }
    }

    const float gate = (EPI == 1 || EPI == 3) ? gate_p[0] : 0.f;
    float bb[NT];
#pragma unroll
    for (int nt = 0; nt < NT; nt++) {
        int n = n0 + wn * WSPAN + nt * 16 + ln;
        if (EPI == 0) {
            int nseg = n >> 9;
            const float* bsel = nseg == 0 ? bias : (nseg == 1 ? bias_b : bias_c);
            bb[nt] = bsel[n - nseg * 512];
        } else {
            bb[nt] = bias[n];
        }
    }
    const bool qkn = (EPI == 0) && ((n0 + wn * WSPAN) < 1024);   // q/k segment: fused L2 norm
#pragma unroll
    for (int mt = 0; mt < MT; mt++) {
        float v[NT][4];
#pragma unroll
        for (int nt = 0; nt < NT; nt++)
#pragma unroll
            for (int r = 0; r < 4; r++) v[nt][r] = acc[mt][nt][r] + bb[nt];
        if (qkn) {
#pragma unroll
            for (int r = 0; r < 4; r++) {
                float s = 0.f;
#pragma unroll
                for (int nt = 0; nt < NT; nt++) s += v[nt][r] * v[nt][r];
                s += __shfl_xor(s, 1); s += __shfl_xor(s, 2);
                s += __shfl_xor(s, 4); s += __shfl_xor(s, 8);
                float rs = 1.f / fmaxf(sqrtf(s), 1e-8f);
#pragma unroll
                for (int nt = 0; nt < NT; nt++) v[nt][r] *= rs;
            }
        }
#pragma unroll
        for (int nt = 0; nt < NT; nt++) {
            int n = n0 + wn * WSPAN + nt * 16 + ln;
#pragma unroll
            for (int r = 0; r < 4; r++) {
                int m = m0 + wm * 64 + mt * 16 + quad * 4 + r;
                size_t off = (size_t)m * N + n;
                float val = v[nt][r];
                if (EPI == 1) val = res[off] + gate * 0.5f * val;
                else if (EPI == 2) val = 0.5f * val * (1.f + erff(val * 0.70710678118654752f));
                else if (EPI == 3) val = fminf(fmaxf(res[off] + gate * val, -10.f), 10.f);
                if (OBF) ((unsigned short*)Cv)[off] = f2b(val);
                else ((float*)Cv)[off] = val;
            }
        }
    }
}

// ---------------- paired flash attention: block handles qt=p and qt=31-p (33 steps, balanced) ----------------
__device__ __forceinline__ void attn_tile_step(
    const unsigned short* Q, unsigned short* Ps, const unsigned short* Ks, const unsigned short* Vt,
    bool diag, fvec4 (&oacc)[4], float (&lp)[4], int w, int quad, int ln)
{
    svec8 a0 = *(const svec8*)(Q + (w * 16 + ln) * 72 + quad * 8);
    svec8 a1 = *(const svec8*)(Q + (w * 16 + ln) * 72 + 32 + quad * 8);
    fvec4 s[4];
#pragma unroll
    for (int nt = 0; nt < 4; nt++) {
#pragma unroll
        for (int r = 0; r < 4; r++) s[nt][r] = 0.f;
        svec8 bk0 = *(const svec8*)(Ks + (nt * 16 + ln) * 72 + quad * 8);
        svec8 bk1 = *(const svec8*)(Ks + (nt * 16 + ln) * 72 + 32 + quad * 8);
        s[nt] = mfma16(a0, bk0, s[nt]);
        s[nt] = mfma16(a1, bk1, s[nt]);
    }
    const int qrow = w * 16 + quad * 4;
#pragma unroll
    for (int nt = 0; nt < 4; nt++) {
        int scol = nt * 16 + ln;
#pragma unroll
        for (int r = 0; r < 4; r++) {
            float p = __builtin_amdgcn_exp2f(s[nt][r] * C1);
            if (diag && scol > qrow + r) p = 0.f;
            lp[r] += p;
            Ps[(qrow + r) * 72 + scol] = f2b(p);
        }
    }
#pragma unroll
    for (int ks = 0; ks < 2; ks++) {
        svec8 pa = *(const svec8*)(Ps + (w * 16 + ln) * 72 + ks * 32 + quad * 8);
#pragma unroll
        for (int nt = 0; nt < 4; nt++) {
            svec8 vb = *(const svec8*)(Vt + (nt * 16 + ln) * 72 + ks * 32 + quad * 8);
            oacc[nt] = mfma16(pa, vb, oacc[nt]);
        }
    }
}

__global__ __launch_bounds__(256)
void attn_pair_kernel(const unsigned short* __restrict__ qkv, const unsigned short* __restrict__ vt,
                      unsigned short* __restrict__ o)
{
    __shared__ __align__(16) unsigned short QA[64 * 72];
    __shared__ __align__(16) unsigned short QB[64 * 72];
    __shared__ __align__(16) unsigned short Ks[64 * 72];
    __shared__ __align__(16) unsigned short Vt[64 * 72];
    __shared__ __align__(16) unsigned short Ps[64 * 72];
    const int p = blockIdx.x, bh = blockIdx.y, b = bh >> 3, hh = bh & 7;
    const int qtA = p, qtB = 31 - p;
    const int tid = threadIdx.x, w = tid >> 6, lane = tid & 63, quad = lane >> 4, ln = lane & 15;
    const int sr = tid >> 2, sc = (tid & 3) * 16;

    {   // stage both Q tiles
        const unsigned short* qgA = qkv + (size_t)(b * T + qtA * 64 + sr) * QS + hh * 64 + sc;
        const unsigned short* qgB = qkv + (size_t)(b * T + qtB * 64 + sr) * QS + hh * 64 + sc;
        uint4 a0 = *(const uint4*)qgA, a1 = *(const uint4*)(qgA + 8);
        uint4 b0 = *(const uint4*)qgB, b1 = *(const uint4*)(qgB + 8);
        *(uint4*)&QA[sr * 72 + sc] = a0; *(uint4*)&QA[sr * 72 + sc + 8] = a1;
        *(uint4*)&QB[sr * 72 + sc] = b0; *(uint4*)&QB[sr * 72 + sc + 8] = b1;
    }

    fvec4 oA[4], oB[4];
    float lA[4] = {0,0,0,0}, lB[4] = {0,0,0,0};
#pragma unroll
    for (int nt = 0; nt < 4; nt++)
#pragma unroll
        for (int r = 0; r < 4; r++) { oA[nt][r] = 0.f; oB[nt][r] = 0.f; }

    const int nst = 32 - p;
    for (int st = 0; st < nst; ++st) {
        const unsigned short* kg = qkv + (size_t)(b * T + st * 64 + sr) * QS + 512 + hh * 64 + sc;
        const unsigned short* vg = vt + (size_t)(bh * 64 + sr) * T + st * 64 + sc;
        uint4 k0 = *(const uint4*)kg, k1 = *(const uint4*)(kg + 8);
        uint4 v0 = *(const uint4*)vg, v1 = *(const uint4*)(vg + 8);
        __syncthreads();   // previous step's MFMA reads of Ks/Vt done (also covers Q staging @ st=0 writes below? no: Q staged pre-loop, read after 2nd barrier)
        *(uint4*)&Ks[sr * 72 + sc] = k0; *(uint4*)&Ks[sr * 72 + sc + 8] = k1;
        *(uint4*)&Vt[sr * 72 + sc] = v0; *(uint4*)&Vt[sr * 72 + sc + 8] = v1;
        __syncthreads();
        attn_tile_step(QB, Ps, Ks, Vt, st == nst - 1, oB, lB, w, quad, ln);
        if (st <= p) attn_tile_step(QA, Ps, Ks, Vt, st == p, oA, lA, w, quad, ln);
    }

    // reduce l over the 16 lanes of each quad-group; write O (bf16)
#pragma unroll
    for (int r = 0; r < 4; r++) {
        float ta = lA[r], tb = lB[r];
        ta += __shfl_xor(ta, 1); ta += __shfl_xor(ta, 2); ta += __shfl_xor(ta, 4); ta += __shfl_xor(ta, 8);
        tb += __shfl_xor(tb, 1); tb += __shfl_xor(tb, 2); tb += __shfl_xor(tb, 4); tb += __shfl_xor(tb, 8);
        lA[r] = ta; lB[r] = tb;
    }
    unsigned short* ogA = o + (size_t)(b * T + qtA * 64 + w * 16 + quad * 4) * D + hh * 64;
    unsigned short* ogB = o + (size_t)(b * T + qtB * 64 + w * 16 + quad * 4) * D + hh * 64;
#pragma unroll
    for (int r = 0; r < 4; r++) {
        float ia = 1.f / lA[r], ib = 1.f / lB[r];
#pragma unroll
        for (int nt = 0; nt < 4; nt++) {
            ogA[(size_t)r * D + nt * 16 + ln] = f2b(oA[nt][r] * ia);
            ogB[(size_t)r * D + nt * 16 + ln] = f2b(oB[nt][r] * ib);
        }
    }
}

// ---------------- masked-mean pool partials ----------------
__global__ __launch_bounds__(256)
void pool_kernel(const float* __restrict__ hn, const float* __restrict__ x, float* __restrict__ part)
{
    int b = blockIdx.x, ch = blockIdx.y, tid = threadIdx.x;
    int t0 = ch * 128;
    float s0 = 0.f, s1 = 0.f, cnt = 0.f;
    for (int tt = 0; tt < 128; tt++) {
        int t = t0 + tt;
        float xv = x[b * T + t];
        float m = (xv == -1.0f) ? 0.f : 1.f;
        cnt += m;
        const float* r = hn + ((size_t)(b * T + t)) * D;
        s0 += r[tid] * m;
        s1 += r[tid + 256] * m;
    }
    float* pr = part + (size_t)(b * 16 + ch) * 513;
    pr[tid] = s0; pr[tid + 256] = s1;
    if (tid == 0) pr[512] = cnt;
}

// ---------------- heads ----------------
__global__ __launch_bounds__(64)
void head_kernel(const float* __restrict__ part,
                 const float* __restrict__ bh_g, const float* __restrict__ bh_bl,
                 const float* __restrict__ ah_g, const float* __restrict__ ah_bl,
                 const float* __restrict__ ch_g, const float* __restrict__ ch_bl,
                 const float* __restrict__ bh_w, const float* __restrict__ bh_b2,
                 const float* __restrict__ ah_w, const float* __restrict__ ah_b2,
                 const float* __restrict__ ch_w, const float* __restrict__ ch_b2,
                 float* __restrict__ out)
{
    int b = blockIdx.x, lane = threadIdx.x;
    float cnt = 0.f;
    for (int c = 0; c < 16; c++) cnt += part[(size_t)(b * 16 + c) * 513 + 512];
    float denom = fmaxf(cnt, 1.f);
    float md[8];
    float s = 0.f, s2 = 0.f;
#pragma unroll
    for (int j = 0; j < 8; j++) {
        int d = j * 64 + lane;
        float acc = 0.f;
        for (int c = 0; c < 16; c++) acc += part[(size_t)(b * 16 + c) * 513 + d];
        md[j] = acc / denom;
        s += md[j]; s2 += md[j] * md[j];
    }
    s = wave_red_sum(s); s2 = wave_red_sum(s2);
    float mu = s * (1.f / 512.f);
    float var = s2 * (1.f / 512.f) - mu * mu;
    float rstd = 1.f / sqrtf(var + 1e-5f);
    float a0 = 0.f, a1 = 0.f, a2 = 0.f, a3 = 0.f;
#pragma unroll
    for (int j = 0; j < 8; j++) {
        int d = j * 64 + lane;
        float z = (md[j] - mu) * rstd;
        float zb = z * bh_g[d] + bh_bl[d];
        a0 += zb * bh_w[d * 2 + 0];
        a1 += zb * bh_w[d * 2 + 1];
        a2 += (z * ah_g[d] + ah_bl[d]) * ah_w[d];
        a3 += (z * ch_g[d] + ch_bl[d]) * ch_w[d];
    }
    a0 = wave_red_sum(a0); a1 = wave_red_sum(a1);
    a2 = wave_red_sum(a2); a3 = wave_red_sum(a3);
    if (lane == 0) {
        out[b * 4 + 0] = a0 + bh_b2[0];
        out[b * 4 + 1] = a1 + bh_b2[1];
        out[b * 4 + 2] = a2 + ah_b2[0];
        float t3 = a3 + ch_b2[0];
        out[b * 4 + 3] = 1.f / (1.f + expf(-t3));
    }
}

// ---------------- launch ----------------
extern "C" void kernel_launch(void* const* d_in, const int* in_sizes, int n_in,
                              void* d_out, int out_size, void* d_ws, size_t ws_size,
                              hipStream_t stream)
{
    const float* x      = (const float*)d_in[0];
    const float* ip_w   = (const float*)d_in[1];
    const float* ip_b   = (const float*)d_in[2];
    const float* ip_ln_g= (const float*)d_in[3];
    const float* ip_ln_b= (const float*)d_in[4];
    const float* pos    = (const float*)d_in[5];
    const float* pad_tok= (const float*)d_in[6];
    const float* Wq = (const float*)d_in[7];  const float* bq = (const float*)d_in[8];
    const float* Wk = (const float*)d_in[9];  const float* bk = (const float*)d_in[10];
    const float* Wv = (const float*)d_in[11]; const float* bv = (const float*)d_in[12];
    const float* Wo = (const float*)d_in[13]; const float* bo = (const float*)d_in[14];
    const float* ln1_g = (const float*)d_in[15]; const float* ln1_b = (const float*)d_in[16];
    const float* ln2_g = (const float*)d_in[17]; const float* ln2_b = (const float*)d_in[18];
    const float* W1 = (const float*)d_in[19]; const float* b1 = (const float*)d_in[20];
    const float* W2 = (const float*)d_in[21]; const float* b2 = (const float*)d_in[22];
    const float* gate1 = (const float*)d_in[23]; const float* gate2 = (const float*)d_in[24];
    const float* fn_g = (const float*)d_in[25]; const float* fn_b = (const float*)d_in[26];
    const float* bh_g  = (const float*)d_in[27]; const float* bh_bl = (const float*)d_in[28];
    const float* ah_g  = (const float*)d_in[29]; const float* ah_bl = (const float*)d_in[30];
    const float* ch_g  = (const float*)d_in[31]; const float* ch_bl = (const float*)d_in[32];
    const float* bh_w  = (const float*)d_in[33]; const float* bh_b2 = (const float*)d_in[34];
    const float* ah_w  = (const float*)d_in[35]; const float* ah_b2 = (const float*)d_in[36];
    const float* ch_w  = (const float*)d_in[37]; const float* ch_b2 = (const float*)d_in[38];

    char* ws = (char*)d_ws;
    float*          h     = (float*)ws;                       // 16 MB fp32 [8192][512]
    unsigned short* act_b = (unsigned short*)(ws + 16777216); // 8 MB bf16 [8192][512]
    unsigned short* qkv   = (unsigned short*)(ws + 25165824); // 24 MB bf16 [8192][1536]
    unsigned short* mid_b = (unsigned short*)(ws + 50331648); // 32 MB bf16 [8192][2048]
    float*          xn_f  = (float*)(ws + 50331648);          // 16 MB alias (final LN only)
    unsigned short* wT    = (unsigned short*)(ws + 83886080); // 6 MB per-layer transposed weights
    unsigned short* vt    = (unsigned short*)(ws + 90177536); // 8 MB bf16 [32][64][2048]
    float*          part  = (float*)(ws + 98566144);
    float*          out   = (float*)d_out;

    unsigned short* wqT = wT;             // [1536][512] (q,k,v contiguous)
    unsigned short* wkT = wT + 262144;
    unsigned short* wvT = wT + 524288;
    unsigned short* woT = wT + 786432;
    unsigned short* w1T = wT + 1048576;   // [2048][512]
    unsigned short* w2T = wT + 2097152;   // [512][2048]

    embed_kernel<<<dim3(Bsz * T), dim3(64), 0, stream>>>(x, ip_w, ip_b, ip_ln_g, ip_ln_b, pos, pad_tok, h);

    for (int i = 0; i < Lnum; i++) {
        const size_t dd = (size_t)i * D * D;
        const size_t df = (size_t)i * D * DFF;
        wconv_kernel<<<dim3(3072), dim3(256), 0, stream>>>(Wq + dd, Wk + dd, Wv + dd, Wo + dd,
                                                           W1 + df, W2 + df,
                                                           wqT, wkT, wvT, woT, w1T, w2T);
        ln_bf16_kernel<<<dim3(Bsz * T), dim3(64), 0, stream>>>(h, act_b, ln1_g + i * D, ln1_b + i * D);
        // fused QKV (+bias, + q/k L2-norm in epilogue): [8192,512]@[512,1536] -> qkv bf16
        gemm_bf16<0, 1, 128><<<dim3(12, 64), dim3(256), 0, stream>>>(act_b, wqT, bq + i * D, bk + i * D, bv + i * D,
                                                                     nullptr, qkv, Bsz * T, QS, D, nullptr);
        vtrans_kernel<<<dim3(32, 32), dim3(256), 0, stream>>>(qkv, vt);
        attn_pair_kernel<<<dim3(16, 32), dim3(256), 0, stream>>>(qkv, vt, act_b);
        gemm_bf16<1, 0, 64><<<dim3(4, 128), dim3(256), 0, stream>>>(act_b, woT, bo + i * D, nullptr, nullptr,
                                                                    h, h, Bsz * T, D, D, gate1 + i);
        ln_bf16_kernel<<<dim3(Bsz * T), dim3(64), 0, stream>>>(h, act_b, ln2_g + i * D, ln2_b + i * D);
        gemm_bf16<2, 1, 128><<<dim3(16, 64), dim3(256), 0, stream>>>(act_b, w1T, b1 + i * DFF, nullptr, nullptr,
                                                                     nullptr, mid_b, Bsz * T, DFF, D, nullptr);
        gemm_bf16<3, 0, 64><<<dim3(4, 128), dim3(256), 0, stream>>>(mid_b, w2T, b2 + i * D, nullptr, nullptr,
                                                                    h, h, Bsz * T, D, DFF, gate2 + i);
    }

    ln_kernel<<<dim3(Bsz * T), dim3(64), 0, stream>>>(h, xn_f, fn_g, fn_b);
    pool_kernel<<<dim3(Bsz, 16), dim3(256), 0, stream>>>(xn_f, x, part);
    head_kernel<<<dim3(Bsz), dim3(64), 0, stream>>>(part, bh_g, bh_bl, ah_g, ah_bl, ch_g, ch_bl,
                                                    bh_w, bh_b2, ah_w, ah_b2, ch_w, ch_b2, out);
}

// Round 4
// 1303.417 us; speedup vs baseline: 5.9469x; 1.0096x over previous
//
#include <hip/hip_runtime.h>
#include <math.h>

// ---------------- constants ----------------
constexpr int Bsz = 4, T = 2048, D = 512, H = 8, Lnum = 6, DFF = 2048, DK = 64;
constexpr int QS2 = 1024;                       // qkv row stride (q at 0, k at 512; v goes to vt)
constexpr float SCALE = 0.08838834764831845f;   // 1/sqrt(128)
constexpr float K2 = 0.08838834764831845f / 1.5f;  // softmax exponent scale (natural log units)

typedef __attribute__((ext_vector_type(8))) short svec8;   // 8 bf16 (4 VGPRs)
typedef __attribute__((ext_vector_type(4))) float fvec4;   // 4 fp32 acc

__device__ __forceinline__ fvec4 mfma16(svec8 a, svec8 b, fvec4 c) {
    return __builtin_amdgcn_mfma_f32_16x16x32_bf16(a, b, c, 0, 0, 0);
}
__device__ __forceinline__ unsigned short f2b(float f) {
    unsigned int u = __float_as_uint(f);
    u += 0x7fffu + ((u >> 16) & 1u);
    return (unsigned short)(u >> 16);
}
__device__ __forceinline__ float wave_red_sum(float v) {
    for (int o = 32; o > 0; o >>= 1) v += __shfl_down(v, o, 64);
    return __shfl(v, 0, 64);
}
// async global->LDS, 16B per lane; lds base must be wave-uniform (HW adds lane*16)
__device__ __forceinline__ void glds16(const unsigned short* g, unsigned short* l) {
    __builtin_amdgcn_global_load_lds(
        (const __attribute__((address_space(1))) unsigned int*)g,
        (__attribute__((address_space(3))) unsigned int*)l, 16, 0, 0);
}
// swizzled-tile fragment read: 64-wide rows, chunk kq of row r at slot kq^(r&7)
#define FRAG(buf, row, kq) (*(const svec8*)((buf) + (((row) << 6) | ((((kq) ^ ((row) & 7))) << 3))))

// ---------------- embed (fp32 h) ----------------
__global__ __launch_bounds__(64)
void embed_kernel(const float* __restrict__ x, const float* __restrict__ ip_w,
                  const float* __restrict__ ip_b, const float* __restrict__ g,
                  const float* __restrict__ bta, const float* __restrict__ pos,
                  const float* __restrict__ pad_tok, float* __restrict__ h)
{
    int row = blockIdx.x;
    int t = row & (T - 1);
    int lane = threadIdx.x;
    float xv = x[row];
    float xc = fminf(fmaxf(xv, -10.f), 10.f);
    bool pad = (xc == -1.0f);
    float pre[8];
    float s = 0.f, s2 = 0.f;
#pragma unroll
    for (int j = 0; j < 8; j++) {
        int d = j * 64 + lane;
        float p = xc * ip_w[d] + ip_b[d];
        pre[j] = p; s += p; s2 += p * p;
    }
    s = wave_red_sum(s); s2 = wave_red_sum(s2);
    float m = s * (1.f / 512.f);
    float var = s2 * (1.f / 512.f) - m * m;
    float rstd = 1.f / sqrtf(var + 1e-5f);
#pragma unroll
    for (int j = 0; j < 8; j++) {
        int d = j * 64 + lane;
        float hv = (pre[j] - m) * rstd * g[d] + bta[d] + 0.1f * pos[(size_t)t * D + d];
        if (pad) hv = pad_tok[d];
        h[(size_t)row * D + d] = hv;
    }
}

// ---------------- LayerNorm fp32 -> fp32 (final), 4 rows/block ----------------
__global__ __launch_bounds__(256)
void ln_kernel(const float* __restrict__ in, float* __restrict__ out,
               const float* __restrict__ g, const float* __restrict__ b)
{
    int row = blockIdx.x * 4 + (threadIdx.x >> 6);
    int lane = threadIdx.x & 63;
    const float* r = in + (size_t)row * D;
    float4 v0 = ((const float4*)r)[lane];
    float4 v1 = ((const float4*)r)[lane + 64];
    float s = v0.x + v0.y + v0.z + v0.w + v1.x + v1.y + v1.z + v1.w;
    float s2 = v0.x*v0.x + v0.y*v0.y + v0.z*v0.z + v0.w*v0.w
             + v1.x*v1.x + v1.y*v1.y + v1.z*v1.z + v1.w*v1.w;
    s = wave_red_sum(s); s2 = wave_red_sum(s2);
    float m = s * (1.f / 512.f);
    float var = s2 * (1.f / 512.f) - m * m;
    float rstd = 1.f / sqrtf(var + 1e-5f);
    float4 g0 = ((const float4*)g)[lane], g1 = ((const float4*)g)[lane + 64];
    float4 b0 = ((const float4*)b)[lane], b1 = ((const float4*)b)[lane + 64];
    float4 o0, o1;
    o0.x = (v0.x - m) * rstd * g0.x + b0.x; o0.y = (v0.y - m) * rstd * g0.y + b0.y;
    o0.z = (v0.z - m) * rstd * g0.z + b0.z; o0.w = (v0.w - m) * rstd * g0.w + b0.w;
    o1.x = (v1.x - m) * rstd * g1.x + b1.x; o1.y = (v1.y - m) * rstd * g1.y + b1.y;
    o1.z = (v1.z - m) * rstd * g1.z + b1.z; o1.w = (v1.w - m) * rstd * g1.w + b1.w;
    ((float4*)(out + (size_t)row * D))[lane] = o0;
    ((float4*)(out + (size_t)row * D))[lane + 64] = o1;
}

// ---------------- LayerNorm fp32 -> bf16, 4 rows/block ----------------
__global__ __launch_bounds__(256)
void ln_bf16_kernel(const float* __restrict__ in, unsigned short* __restrict__ out,
                    const float* __restrict__ g, const float* __restrict__ b)
{
    int row = blockIdx.x * 4 + (threadIdx.x >> 6);
    int lane = threadIdx.x & 63;
    const float* r = in + (size_t)row * D;
    float4 v0 = ((const float4*)r)[lane];
    float4 v1 = ((const float4*)r)[lane + 64];
    float s = v0.x + v0.y + v0.z + v0.w + v1.x + v1.y + v1.z + v1.w;
    float s2 = v0.x*v0.x + v0.y*v0.y + v0.z*v0.z + v0.w*v0.w
             + v1.x*v1.x + v1.y*v1.y + v1.z*v1.z + v1.w*v1.w;
    s = wave_red_sum(s); s2 = wave_red_sum(s2);
    float m = s * (1.f / 512.f);
    float var = s2 * (1.f / 512.f) - m * m;
    float rstd = 1.f / sqrtf(var + 1e-5f);
    float4 g0 = ((const float4*)g)[lane], g1 = ((const float4*)g)[lane + 64];
    float4 b0 = ((const float4*)b)[lane], b1 = ((const float4*)b)[lane + 64];
    unsigned short o0[4], o1[4];
    o0[0] = f2b((v0.x - m) * rstd * g0.x + b0.x); o0[1] = f2b((v0.y - m) * rstd * g0.y + b0.y);
    o0[2] = f2b((v0.z - m) * rstd * g0.z + b0.z); o0[3] = f2b((v0.w - m) * rstd * g0.w + b0.w);
    o1[0] = f2b((v1.x - m) * rstd * g1.x + b1.x); o1[1] = f2b((v1.y - m) * rstd * g1.y + b1.y);
    o1[2] = f2b((v1.z - m) * rstd * g1.z + b1.z); o1[3] = f2b((v1.w - m) * rstd * g1.w + b1.w);
    *(uint2*)(out + (size_t)row * D + lane * 4) = *(uint2*)o0;
    *(uint2*)(out + (size_t)row * D + 256 + lane * 4) = *(uint2*)o1;
}

// ---------------- weight transpose + cast: fp32 [K][N] -> bf16 [N][K], per layer ----------------
__global__ __launch_bounds__(256)
void wconv_kernel(const float* __restrict__ wq, const float* __restrict__ wk,
                  const float* __restrict__ wv, const float* __restrict__ wo,
                  const float* __restrict__ w1, const float* __restrict__ w2,
                  unsigned short* __restrict__ oq, unsigned short* __restrict__ ok,
                  unsigned short* __restrict__ ov, unsigned short* __restrict__ oo,
                  unsigned short* __restrict__ o1, unsigned short* __restrict__ o2)
{
    __shared__ float tile[32][33];
    int bid = blockIdx.x;
    const float* in; unsigned short* out; int K, N, kt, nt;
    if (bid < 1024) {
        int sel = bid >> 8, loc = bid & 255;
        in  = sel == 0 ? wq : sel == 1 ? wk : sel == 2 ? wv : wo;
        out = sel == 0 ? oq : sel == 1 ? ok : sel == 2 ? ov : oo;
        K = 512; N = 512; kt = loc >> 4; nt = loc & 15;
    } else if (bid < 2048) {
        int loc = bid - 1024; in = w1; out = o1; K = 512; N = 2048; kt = loc >> 6; nt = loc & 63;
    } else {
        int loc = bid - 2048; in = w2; out = o2; K = 2048; N = 512; kt = loc >> 4; nt = loc & 15;
    }
    int k0 = kt * 32, n0 = nt * 32;
    int t = threadIdx.x;
    int kr = t >> 3, nc = (t & 7) * 4;
    float4 v = *(const float4*)(in + (size_t)(k0 + kr) * N + n0 + nc);
    tile[kr][nc] = v.x; tile[kr][nc + 1] = v.y; tile[kr][nc + 2] = v.z; tile[kr][nc + 3] = v.w;
    __syncthreads();
    unsigned short o[4];
#pragma unroll
    for (int i = 0; i < 4; i++) o[i] = f2b(tile[nc + i][kr]);
    *(uint2*)(out + (size_t)(n0 + kr) * K + k0 + nc) = *(uint2*)o;
}

// ---------------- bf16 MFMA GEMM, global_load_lds + BK=64 XOR swizzle ----------------
// EPI 0: qkv fused (q/k -> qkv stride 1024 w/ fused L2-norm; v -> vt transposed)
// EPI 1: res + gate*0.5*v (fp32 out)   EPI 2: gelu exact (bf16 out)   EPI 3: clip(res+gate*v,+-10) (fp32 out)
template<int EPI, int OBF, int BM>
__global__ __launch_bounds__(256)
void gemm_bf16(const unsigned short* __restrict__ A, const unsigned short* __restrict__ BT,
               const float* __restrict__ bias, const float* __restrict__ bias_b,
               const float* __restrict__ bias_c, const float* __restrict__ res,
               void* __restrict__ Cv, unsigned short* __restrict__ vtout,
               int M, int N, int K, const float* __restrict__ gate_p)
{
    constexpr int WN = (BM == 128) ? 2 : 4;
    constexpr int WSPAN = 128 / WN;
    constexpr int NT = WSPAN / 16;
    constexpr int MT = 4;
    constexpr int ACALLS = BM / 32;
    __shared__ __align__(16) unsigned short As[BM * 64];
    __shared__ __align__(16) unsigned short Bs[128 * 64];
    const int tid = threadIdx.x, w = tid >> 6, lane = tid & 63, quad = lane >> 4, ln = lane & 15;
    const int wm = w / WN, wn = w % WN;
    const int m0 = blockIdx.y * BM, n0 = blockIdx.x * 128;
    const int jg = (lane & 7) ^ ((lane >> 3) & 7);
    const int rb = w * 8 + (lane >> 3);
    const unsigned short* Agl = A + (size_t)(m0 + rb) * K + jg * 8;
    const unsigned short* Bgl = BT + (size_t)(n0 + rb) * K + jg * 8;

    fvec4 acc[MT][NT];
#pragma unroll
    for (int mt = 0; mt < MT; mt++)
#pragma unroll
        for (int nt = 0; nt < NT; nt++)
#pragma unroll
            for (int r = 0; r < 4; r++) acc[mt][nt][r] = 0.f;

    for (int k0 = 0; k0 < K; k0 += 64) {
        __syncthreads();
#pragma unroll
        for (int c = 0; c < ACALLS; c++)
            glds16(Agl + k0 + (size_t)c * 32 * K, As + c * 2048 + w * 512);
#pragma unroll
        for (int c = 0; c < 4; c++)
            glds16(Bgl + k0 + (size_t)c * 32 * K, Bs + c * 2048 + w * 512);
        __syncthreads();
#pragma unroll
        for (int kk = 0; kk < 2; kk++) {
            svec8 af[MT], bfr[NT];
#pragma unroll
            for (int mt = 0; mt < MT; mt++)
                af[mt] = FRAG(As, wm * 64 + mt * 16 + ln, kk * 4 + quad);
#pragma unroll
            for (int nt = 0; nt < NT; nt++)
                bfr[nt] = FRAG(Bs, wn * WSPAN + nt * 16 + ln, kk * 4 + quad);
#pragma unroll
            for (int mt = 0; mt < MT; mt++)
#pragma unroll
                for (int nt = 0; nt < NT; nt++)
                    acc[mt][nt] = mfma16(af[mt], bfr[nt], acc[mt][nt]);
        }
    }

    const float gate = (EPI == 1 || EPI == 3) ? gate_p[0] : 0.f;
    float bb[NT];
#pragma unroll
    for (int nt = 0; nt < NT; nt++) {
        int n = n0 + wn * WSPAN + nt * 16 + ln;
        if (EPI == 0) {
            int nseg = n >> 9;
            const float* bsel = nseg == 0 ? bias : (nseg == 1 ? bias_b : bias_c);
            bb[nt] = bsel[n - nseg * 512];
        } else {
            bb[nt] = bias[n];
        }
    }
    const bool qkn = (EPI == 0) && ((n0 + wn * WSPAN) < 1024);
#pragma unroll
    for (int mt = 0; mt < MT; mt++) {
        float v[NT][4];
#pragma unroll
        for (int nt = 0; nt < NT; nt++)
#pragma unroll
            for (int r = 0; r < 4; r++) v[nt][r] = acc[mt][nt][r] + bb[nt];
        if (qkn) {
#pragma unroll
            for (int r = 0; r < 4; r++) {
                float s = 0.f;
#pragma unroll
                for (int nt = 0; nt < NT; nt++) s += v[nt][r] * v[nt][r];
                s += __shfl_xor(s, 1); s += __shfl_xor(s, 2);
                s += __shfl_xor(s, 4); s += __shfl_xor(s, 8);
                float rs = 1.f / fmaxf(sqrtf(s), 1e-8f);
#pragma unroll
                for (int nt = 0; nt < NT; nt++) v[nt][r] *= rs;
            }
        }
#pragma unroll
        for (int nt = 0; nt < NT; nt++) {
            int n = n0 + wn * WSPAN + nt * 16 + ln;
#pragma unroll
            for (int r = 0; r < 4; r++) {
                int m = m0 + wm * 64 + mt * 16 + quad * 4 + r;
                float val = v[nt][r];
                if (EPI == 0) {
                    if (n < 1024) ((unsigned short*)Cv)[(size_t)m * QS2 + n] = f2b(val);
                    else vtout[((size_t)((m >> 11) * 512 + (n - 1024))) * T + (m & (T - 1))] = f2b(val);
                } else {
                    size_t off = (size_t)m * N + n;
                    if (EPI == 1) val = res[off] + gate * 0.5f * val;
                    else if (EPI == 2) val = 0.5f * val * (1.f + erff(val * 0.70710678118654752f));
                    else if (EPI == 3) val = fminf(fmaxf(res[off] + gate * val, -10.f), 10.f);
                    if (OBF) ((unsigned short*)Cv)[off] = f2b(val);
                    else ((float*)Cv)[off] = val;
                }
            }
        }
    }
}

// ---------------- paired flash attention, async glds staging, 2 s-tiles/barrier ----------------
__device__ __forceinline__ void attn_step(
    const unsigned short* Q, unsigned short* Ps, const unsigned short* Ks, const unsigned short* Vt,
    bool diag, fvec4 (&oacc)[4], float (&lp)[4], int w, int quad, int ln)
{
    svec8 a0 = FRAG(Q, w * 16 + ln, quad);
    svec8 a1 = FRAG(Q, w * 16 + ln, 4 + quad);
    fvec4 s[4];
#pragma unroll
    for (int nt = 0; nt < 4; nt++) {
#pragma unroll
        for (int r = 0; r < 4; r++) s[nt][r] = 0.f;
        s[nt] = mfma16(a0, FRAG(Ks, nt * 16 + ln, quad), s[nt]);
        s[nt] = mfma16(a1, FRAG(Ks, nt * 16 + ln, 4 + quad), s[nt]);
    }
    const int qrow = w * 16 + quad * 4;
#pragma unroll
    for (int nt = 0; nt < 4; nt++) {
        int col = nt * 16 + ln;
#pragma unroll
        for (int r = 0; r < 4; r++) {
            // e^y, y = s*SCALE/1.5 in [-0.059,0.059]: cubic Taylor, err < 6e-7 << bf16 P-quantization
            float y = s[nt][r] * K2;
            float p = fmaf(y, fmaf(y, fmaf(y, 0.16666667f, 0.5f), 1.f), 1.f);
            if (diag && col > qrow + r) p = 0.f;
            lp[r] += p;
            int row = qrow + r;
            Ps[(row << 6) | ((((col >> 3) ^ (row & 7))) << 3) | (col & 7)] = f2b(p);
        }
    }
#pragma unroll
    for (int ks = 0; ks < 2; ks++) {
        svec8 pa = FRAG(Ps, w * 16 + ln, ks * 4 + quad);
#pragma unroll
        for (int nt = 0; nt < 4; nt++)
            oacc[nt] = mfma16(pa, FRAG(Vt, nt * 16 + ln, ks * 4 + quad), oacc[nt]);
    }
}

__global__ __launch_bounds__(256)
void attn_pair_kernel(const unsigned short* __restrict__ qkv, const unsigned short* __restrict__ vt,
                      unsigned short* __restrict__ o)
{
    __shared__ __align__(16) unsigned short QA[4096], QB[4096];
    __shared__ __align__(16) unsigned short K0[4096], V0[4096], K1[4096], V1[4096];
    __shared__ __align__(16) unsigned short Ps[4096];
    const int p = blockIdx.x, bh = blockIdx.y, b = bh >> 3, hh = bh & 7;
    const int qtA = p, qtB = 31 - p, nst = 32 - p;   // B: st 0..nst-1; A: st 0..p
    const int tid = threadIdx.x, w = tid >> 6, lane = tid & 63, quad = lane >> 4, ln = lane & 15;
    const int rl = lane >> 3, sl = lane & 7, jgz = sl ^ rl;
    const int w8 = w * 8;
    const int grow = w8 + rl;
    const unsigned short* qrow_p = qkv + ((size_t)(b * T) + grow) * QS2 + hh * 64 + jgz * 8;
    const unsigned short* krow_p = qrow_p + 512;
    const unsigned short* vrow_p = vt + ((size_t)(bh * 64) + grow) * T + jgz * 8;

    glds16(qrow_p + (size_t)(qtA * 64) * QS2, QA + w8 * 64);
    glds16(qrow_p + (size_t)(qtA * 64 + 32) * QS2, QA + (w8 + 32) * 64);
    glds16(qrow_p + (size_t)(qtB * 64) * QS2, QB + w8 * 64);
    glds16(qrow_p + (size_t)(qtB * 64 + 32) * QS2, QB + (w8 + 32) * 64);

    fvec4 oA[4], oB[4];
    float lA[4] = {0, 0, 0, 0}, lB[4] = {0, 0, 0, 0};
#pragma unroll
    for (int nt = 0; nt < 4; nt++)
#pragma unroll
        for (int r = 0; r < 4; r++) { oA[nt][r] = 0.f; oB[nt][r] = 0.f; }

    const int Nph = (nst + 1) >> 1;
    for (int ph = 0; ph < Nph; ph++) {
        const int s0 = 2 * ph, s1 = 2 * ph + 1;
        __syncthreads();   // all reads of K0/V0/K1/V1 from previous phase complete
        glds16(krow_p + (size_t)(s0 * 64) * QS2, K0 + w8 * 64);
        glds16(krow_p + (size_t)(s0 * 64 + 32) * QS2, K0 + (w8 + 32) * 64);
        glds16(vrow_p + s0 * 64, V0 + w8 * 64);
        glds16(vrow_p + (size_t)32 * T + s0 * 64, V0 + (w8 + 32) * 64);
        if (s1 < nst) {
            glds16(krow_p + (size_t)(s1 * 64) * QS2, K1 + w8 * 64);
            glds16(krow_p + (size_t)(s1 * 64 + 32) * QS2, K1 + (w8 + 32) * 64);
            glds16(vrow_p + s1 * 64, V1 + w8 * 64);
            glds16(vrow_p + (size_t)32 * T + s1 * 64, V1 + (w8 + 32) * 64);
        }
        __syncthreads();   // vmcnt drained: staged data visible
        attn_step(QB, Ps, K0, V0, s0 == nst - 1, oB, lB, w, quad, ln);
        if (s0 <= p) attn_step(QA, Ps, K0, V0, s0 == p, oA, lA, w, quad, ln);
        if (s1 < nst) {
            attn_step(QB, Ps, K1, V1, s1 == nst - 1, oB, lB, w, quad, ln);
            if (s1 <= p) attn_step(QA, Ps, K1, V1, s1 == p, oA, lA, w, quad, ln);
        }
    }

#pragma unroll
    for (int r = 0; r < 4; r++) {
        float ta = lA[r], tb = lB[r];
        ta += __shfl_xor(ta, 1); ta += __shfl_xor(ta, 2); ta += __shfl_xor(ta, 4); ta += __shfl_xor(ta, 8);
        tb += __shfl_xor(tb, 1); tb += __shfl_xor(tb, 2); tb += __shfl_xor(tb, 4); tb += __shfl_xor(tb, 8);
        lA[r] = ta; lB[r] = tb;
    }
    unsigned short* ogA = o + (size_t)(b * T + qtA * 64 + w * 16 + quad * 4) * D + hh * 64;
    unsigned short* ogB = o + (size_t)(b * T + qtB * 64 + w * 16 + quad * 4) * D + hh * 64;
#pragma unroll
    for (int r = 0; r < 4; r++) {
        float ia = 1.f / lA[r], ib = 1.f / lB[r];
#pragma unroll
        for (int nt = 0; nt < 4; nt++) {
            ogA[(size_t)r * D + nt * 16 + ln] = f2b(oA[nt][r] * ia);
            ogB[(size_t)r * D + nt * 16 + ln] = f2b(oB[nt][r] * ib);
        }
    }
}

// ---------------- masked-mean pool partials ----------------
__global__ __launch_bounds__(256)
void pool_kernel(const float* __restrict__ hn, const float* __restrict__ x, float* __restrict__ part)
{
    int b = blockIdx.x, ch = blockIdx.y, tid = threadIdx.x;
    int t0 = ch * 128;
    float s0 = 0.f, s1 = 0.f, cnt = 0.f;
    for (int tt = 0; tt < 128; tt++) {
        int t = t0 + tt;
        float xv = x[b * T + t];
        float m = (xv == -1.0f) ? 0.f : 1.f;
        cnt += m;
        const float* r = hn + ((size_t)(b * T + t)) * D;
        s0 += r[tid] * m;
        s1 += r[tid + 256] * m;
    }
    float* pr = part + (size_t)(b * 16 + ch) * 513;
    pr[tid] = s0; pr[tid + 256] = s1;
    if (tid == 0) pr[512] = cnt;
}

// ---------------- heads ----------------
__global__ __launch_bounds__(64)
void head_kernel(const float* __restrict__ part,
                 const float* __restrict__ bh_g, const float* __restrict__ bh_bl,
                 const float* __restrict__ ah_g, const float* __restrict__ ah_bl,
                 const float* __restrict__ ch_g, const float* __restrict__ ch_bl,
                 const float* __restrict__ bh_w, const float* __restrict__ bh_b2,
                 const float* __restrict__ ah_w, const float* __restrict__ ah_b2,
                 const float* __restrict__ ch_w, const float* __restrict__ ch_b2,
                 float* __restrict__ out)
{
    int b = blockIdx.x, lane = threadIdx.x;
    float cnt = 0.f;
    for (int c = 0; c < 16; c++) cnt += part[(size_t)(b * 16 + c) * 513 + 512];
    float denom = fmaxf(cnt, 1.f);
    float md[8];
    float s = 0.f, s2 = 0.f;
#pragma unroll
    for (int j = 0; j < 8; j++) {
        int d = j * 64 + lane;
        float acc = 0.f;
        for (int c = 0; c < 16; c++) acc += part[(size_t)(b * 16 + c) * 513 + d];
        md[j] = acc / denom;
        s += md[j]; s2 += md[j] * md[j];
    }
    s = wave_red_sum(s); s2 = wave_red_sum(s2);
    float mu = s * (1.f / 512.f);
    float var = s2 * (1.f / 512.f) - mu * mu;
    float rstd = 1.f / sqrtf(var + 1e-5f);
    float a0 = 0.f, a1 = 0.f, a2 = 0.f, a3 = 0.f;
#pragma unroll
    for (int j = 0; j < 8; j++) {
        int d = j * 64 + lane;
        float z = (md[j] - mu) * rstd;
        float zb = z * bh_g[d] + bh_bl[d];
        a0 += zb * bh_w[d * 2 + 0];
        a1 += zb * bh_w[d * 2 + 1];
        a2 += (z * ah_g[d] + ah_bl[d]) * ah_w[d];
        a3 += (z * ch_g[d] + ch_bl[d]) * ch_w[d];
    }
    a0 = wave_red_sum(a0); a1 = wave_red_sum(a1);
    a2 = wave_red_sum(a2); a3 = wave_red_sum(a3);
    if (lane == 0) {
        out[b * 4 + 0] = a0 + bh_b2[0];
        out[b * 4 + 1] = a1 + bh_b2[1];
        out[b * 4 + 2] = a2 + ah_b2[0];
        float t3 = a3 + ch_b2[0];
        out[b * 4 + 3] = 1.f / (1.f + expf(-t3));
    }
}

// ---------------- launch ----------------
extern "C" void kernel_launch(void* const* d_in, const int* in_sizes, int n_in,
                              void* d_out, int out_size, void* d_ws, size_t ws_size,
                              hipStream_t stream)
{
    const float* x      = (const float*)d_in[0];
    const float* ip_w   = (const float*)d_in[1];
    const float* ip_b   = (const float*)d_in[2];
    const float* ip_ln_g= (const float*)d_in[3];
    const float* ip_ln_b= (const float*)d_in[4];
    const float* pos    = (const float*)d_in[5];
    const float* pad_tok= (const float*)d_in[6];
    const float* Wq = (const float*)d_in[7];  const float* bq = (const float*)d_in[8];
    const float* Wk = (const float*)d_in[9];  const float* bk = (const float*)d_in[10];
    const float* Wv = (const float*)d_in[11]; const float* bv = (const float*)d_in[12];
    const float* Wo = (const float*)d_in[13]; const float* bo = (const float*)d_in[14];
    const float* ln1_g = (const float*)d_in[15]; const float* ln1_b = (const float*)d_in[16];
    const float* ln2_g = (const float*)d_in[17]; const float* ln2_b = (const float*)d_in[18];
    const float* W1 = (const float*)d_in[19]; const float* b1 = (const float*)d_in[20];
    const float* W2 = (const float*)d_in[21]; const float* b2 = (const float*)d_in[22];
    const float* gate1 = (const float*)d_in[23]; const float* gate2 = (const float*)d_in[24];
    const float* fn_g = (const float*)d_in[25]; const float* fn_b = (const float*)d_in[26];
    const float* bh_g  = (const float*)d_in[27]; const float* bh_bl = (const float*)d_in[28];
    const float* ah_g  = (const float*)d_in[29]; const float* ah_bl = (const float*)d_in[30];
    const float* ch_g  = (const float*)d_in[31]; const float* ch_bl = (const float*)d_in[32];
    const float* bh_w  = (const float*)d_in[33]; const float* bh_b2 = (const float*)d_in[34];
    const float* ah_w  = (const float*)d_in[35]; const float* ah_b2 = (const float*)d_in[36];
    const float* ch_w  = (const float*)d_in[37]; const float* ch_b2 = (const float*)d_in[38];

    char* ws = (char*)d_ws;
    float*          h     = (float*)ws;                       // 16 MB fp32 [8192][512]
    unsigned short* act_b = (unsigned short*)(ws + 16777216); // 8 MB bf16 [8192][512]
    unsigned short* qkv   = (unsigned short*)(ws + 25165824); // 16 MB bf16 [8192][1024] (q|k)
    unsigned short* mid_b = (unsigned short*)(ws + 41943040); // 32 MB bf16 [8192][2048]
    float*          xn_f  = (float*)(ws + 41943040);          // 16 MB alias (final LN only)
    unsigned short* wT    = (unsigned short*)(ws + 75497472); // 6 MB per-layer transposed weights
    unsigned short* vt    = (unsigned short*)(ws + 81788928); // 8 MB bf16 [32*64][2048]
    float*          part  = (float*)(ws + 90177536);
    float*          out   = (float*)d_out;

    unsigned short* wqT = wT;             // [1536][512] (q,k,v contiguous)
    unsigned short* wkT = wT + 262144;
    unsigned short* wvT = wT + 524288;
    unsigned short* woT = wT + 786432;
    unsigned short* w1T = wT + 1048576;   // [2048][512]
    unsigned short* w2T = wT + 2097152;   // [512][2048]

    embed_kernel<<<dim3(Bsz * T), dim3(64), 0, stream>>>(x, ip_w, ip_b, ip_ln_g, ip_ln_b, pos, pad_tok, h);

    for (int i = 0; i < Lnum; i++) {
        const size_t dd = (size_t)i * D * D;
        const size_t df = (size_t)i * D * DFF;
        wconv_kernel<<<dim3(3072), dim3(256), 0, stream>>>(Wq + dd, Wk + dd, Wv + dd, Wo + dd,
                                                           W1 + df, W2 + df,
                                                           wqT, wkT, wvT, woT, w1T, w2T);
        ln_bf16_kernel<<<dim3(Bsz * T / 4), dim3(256), 0, stream>>>(h, act_b, ln1_g + i * D, ln1_b + i * D);
        gemm_bf16<0, 1, 128><<<dim3(12, 64), dim3(256), 0, stream>>>(act_b, wqT, bq + i * D, bk + i * D, bv + i * D,
                                                                     nullptr, qkv, vt, Bsz * T, 1536, D, nullptr);
        attn_pair_kernel<<<dim3(16, 32), dim3(256), 0, stream>>>(qkv, vt, act_b);
        gemm_bf16<1, 0, 64><<<dim3(4, 128), dim3(256), 0, stream>>>(act_b, woT, bo + i * D, nullptr, nullptr,
                                                                    h, h, nullptr, Bsz * T, D, D, gate1 + i);
        ln_bf16_kernel<<<dim3(Bsz * T / 4), dim3(256), 0, stream>>>(h, act_b, ln2_g + i * D, ln2_b + i * D);
        gemm_bf16<2, 1, 128><<<dim3(16, 64), dim3(256), 0, stream>>>(act_b, w1T, b1 + i * DFF, nullptr, nullptr,
                                                                     nullptr, mid_b, nullptr, Bsz * T, DFF, D, nullptr);
        gemm_bf16<3, 0, 64><<<dim3(4, 128), dim3(256), 0, stream>>>(mid_b, w2T, b2 + i * D, nullptr, nullptr,
                                                                    h, h, nullptr, Bsz * T, D, DFF, gate2 + i);
    }

    ln_kernel<<<dim3(Bsz * T / 4), dim3(256), 0, stream>>>(h, xn_f, fn_g, fn_b);
    pool_kernel<<<dim3(Bsz, 16), dim3(256), 0, stream>>>(xn_f, x, part);
    head_kernel<<<dim3(Bsz), dim3(64), 0, stream>>>(part, bh_g, bh_bl, ah_g, ah_bl, ch_g, ch_bl,
                                                    bh_w, bh_b2, ah_w, ah_b2, ch_w, ch_b2, out);
}

// Round 5
// 1227.661 us; speedup vs baseline: 6.3138x; 1.0617x over previous
//
#include <hip/hip_runtime.h>
#include <hip/hip_bf16.h>
#include <math.h>

// ---------------- constants ----------------
constexpr int Bsz = 4, T = 2048, D = 512, H = 8, Lnum = 6, DFF = 2048, DK = 64;
constexpr int QS2 = 1024;                       // qkv row stride (q at 0, k at 512; v goes to vt)
constexpr float K2 = 0.08838834764831845f / 1.5f;  // softmax exponent scale

typedef __attribute__((ext_vector_type(8))) short svec8;   // 8 bf16 (4 VGPRs)
typedef __attribute__((ext_vector_type(4))) float fvec4;   // 4 fp32 acc

__device__ __forceinline__ fvec4 mfma16(svec8 a, svec8 b, fvec4 c) {
    return __builtin_amdgcn_mfma_f32_16x16x32_bf16(a, b, c, 0, 0, 0);
}
__device__ __forceinline__ unsigned short f2b(float f) {
    unsigned int u = __float_as_uint(f);
    u += 0x7fffu + ((u >> 16) & 1u);
    return (unsigned short)(u >> 16);
}
__device__ __forceinline__ unsigned int pk2b(float a, float b) {
    __hip_bfloat162 h = __float22bfloat162_rn(float2{a, b});
    return *(unsigned int*)&h;
}
__device__ __forceinline__ float wave_red_sum(float v) {
    for (int o = 32; o > 0; o >>= 1) v += __shfl_down(v, o, 64);
    return __shfl(v, 0, 64);
}
// async global->LDS, 16B per lane; lds base must be wave-uniform (HW adds lane*16)
__device__ __forceinline__ void glds16(const unsigned short* g, unsigned short* l) {
    __builtin_amdgcn_global_load_lds(
        (const __attribute__((address_space(1))) unsigned int*)g,
        (__attribute__((address_space(3))) unsigned int*)l, 16, 0, 0);
}
// swizzled-tile fragment read: 64-wide rows, chunk kq of row r at slot kq^(r&7)
#define FRAG(buf, row, kq) (*(const svec8*)((buf) + (((row) << 6) | ((((kq) ^ ((row) & 7))) << 3))))

// ---------------- embed (fp32 h) ----------------
__global__ __launch_bounds__(64)
void embed_kernel(const float* __restrict__ x, const float* __restrict__ ip_w,
                  const float* __restrict__ ip_b, const float* __restrict__ g,
                  const float* __restrict__ bta, const float* __restrict__ pos,
                  const float* __restrict__ pad_tok, float* __restrict__ h)
{
    int row = blockIdx.x;
    int t = row & (T - 1);
    int lane = threadIdx.x;
    float xv = x[row];
    float xc = fminf(fmaxf(xv, -10.f), 10.f);
    bool pad = (xc == -1.0f);
    float pre[8];
    float s = 0.f, s2 = 0.f;
#pragma unroll
    for (int j = 0; j < 8; j++) {
        int d = j * 64 + lane;
        float p = xc * ip_w[d] + ip_b[d];
        pre[j] = p; s += p; s2 += p * p;
    }
    s = wave_red_sum(s); s2 = wave_red_sum(s2);
    float m = s * (1.f / 512.f);
    float var = s2 * (1.f / 512.f) - m * m;
    float rstd = 1.f / sqrtf(var + 1e-5f);
#pragma unroll
    for (int j = 0; j < 8; j++) {
        int d = j * 64 + lane;
        float hv = (pre[j] - m) * rstd * g[d] + bta[d] + 0.1f * pos[(size_t)t * D + d];
        if (pad) hv = pad_tok[d];
        h[(size_t)row * D + d] = hv;
    }
}

// ---------------- LayerNorm fp32 -> fp32 (final), 4 rows/block ----------------
__global__ __launch_bounds__(256)
void ln_kernel(const float* __restrict__ in, float* __restrict__ out,
               const float* __restrict__ g, const float* __restrict__ b)
{
    int row = blockIdx.x * 4 + (threadIdx.x >> 6);
    int lane = threadIdx.x & 63;
    const float* r = in + (size_t)row * D;
    float4 v0 = ((const float4*)r)[lane];
    float4 v1 = ((const float4*)r)[lane + 64];
    float s = v0.x + v0.y + v0.z + v0.w + v1.x + v1.y + v1.z + v1.w;
    float s2 = v0.x*v0.x + v0.y*v0.y + v0.z*v0.z + v0.w*v0.w
             + v1.x*v1.x + v1.y*v1.y + v1.z*v1.z + v1.w*v1.w;
    s = wave_red_sum(s); s2 = wave_red_sum(s2);
    float m = s * (1.f / 512.f);
    float var = s2 * (1.f / 512.f) - m * m;
    float rstd = 1.f / sqrtf(var + 1e-5f);
    float4 g0 = ((const float4*)g)[lane], g1 = ((const float4*)g)[lane + 64];
    float4 b0 = ((const float4*)b)[lane], b1 = ((const float4*)b)[lane + 64];
    float4 o0, o1;
    o0.x = (v0.x - m) * rstd * g0.x + b0.x; o0.y = (v0.y - m) * rstd * g0.y + b0.y;
    o0.z = (v0.z - m) * rstd * g0.z + b0.z; o0.w = (v0.w - m) * rstd * g0.w + b0.w;
    o1.x = (v1.x - m) * rstd * g1.x + b1.x; o1.y = (v1.y - m) * rstd * g1.y + b1.y;
    o1.z = (v1.z - m) * rstd * g1.z + b1.z; o1.w = (v1.w - m) * rstd * g1.w + b1.w;
    ((float4*)(out + (size_t)row * D))[lane] = o0;
    ((float4*)(out + (size_t)row * D))[lane + 64] = o1;
}

// ---------------- LayerNorm fp32 -> bf16, 4 rows/block ----------------
__global__ __launch_bounds__(256)
void ln_bf16_kernel(const float* __restrict__ in, unsigned short* __restrict__ out,
                    const float* __restrict__ g, const float* __restrict__ b)
{
    int row = blockIdx.x * 4 + (threadIdx.x >> 6);
    int lane = threadIdx.x & 63;
    const float* r = in + (size_t)row * D;
    float4 v0 = ((const float4*)r)[lane];
    float4 v1 = ((const float4*)r)[lane + 64];
    float s = v0.x + v0.y + v0.z + v0.w + v1.x + v1.y + v1.z + v1.w;
    float s2 = v0.x*v0.x + v0.y*v0.y + v0.z*v0.z + v0.w*v0.w
             + v1.x*v1.x + v1.y*v1.y + v1.z*v1.z + v1.w*v1.w;
    s = wave_red_sum(s); s2 = wave_red_sum(s2);
    float m = s * (1.f / 512.f);
    float var = s2 * (1.f / 512.f) - m * m;
    float rstd = 1.f / sqrtf(var + 1e-5f);
    float4 g0 = ((const float4*)g)[lane], g1 = ((const float4*)g)[lane + 64];
    float4 b0 = ((const float4*)b)[lane], b1 = ((const float4*)b)[lane + 64];
    unsigned short o0[4], o1[4];
    o0[0] = f2b((v0.x - m) * rstd * g0.x + b0.x); o0[1] = f2b((v0.y - m) * rstd * g0.y + b0.y);
    o0[2] = f2b((v0.z - m) * rstd * g0.z + b0.z); o0[3] = f2b((v0.w - m) * rstd * g0.w + b0.w);
    o1[0] = f2b((v1.x - m) * rstd * g1.x + b1.x); o1[1] = f2b((v1.y - m) * rstd * g1.y + b1.y);
    o1[2] = f2b((v1.z - m) * rstd * g1.z + b1.z); o1[3] = f2b((v1.w - m) * rstd * g1.w + b1.w);
    *(uint2*)(out + (size_t)row * D + lane * 4) = *(uint2*)o0;
    *(uint2*)(out + (size_t)row * D + 256 + lane * 4) = *(uint2*)o1;
}

// ---------------- weight transpose + cast: fp32 [K][N] -> bf16 [N][K], per layer ----------------
__global__ __launch_bounds__(256)
void wconv_kernel(const float* __restrict__ wq, const float* __restrict__ wk,
                  const float* __restrict__ wv, const float* __restrict__ wo,
                  const float* __restrict__ w1, const float* __restrict__ w2,
                  unsigned short* __restrict__ oq, unsigned short* __restrict__ ok,
                  unsigned short* __restrict__ ov, unsigned short* __restrict__ oo,
                  unsigned short* __restrict__ o1, unsigned short* __restrict__ o2)
{
    __shared__ float tile[32][33];
    int bid = blockIdx.x;
    const float* in; unsigned short* out; int K, N, kt, nt;
    if (bid < 1024) {
        int sel = bid >> 8, loc = bid & 255;
        in  = sel == 0 ? wq : sel == 1 ? wk : sel == 2 ? wv : wo;
        out = sel == 0 ? oq : sel == 1 ? ok : sel == 2 ? ov : oo;
        K = 512; N = 512; kt = loc >> 4; nt = loc & 15;
    } else if (bid < 2048) {
        int loc = bid - 1024; in = w1; out = o1; K = 512; N = 2048; kt = loc >> 6; nt = loc & 63;
    } else {
        int loc = bid - 2048; in = w2; out = o2; K = 2048; N = 512; kt = loc >> 4; nt = loc & 15;
    }
    int k0 = kt * 32, n0 = nt * 32;
    int t = threadIdx.x;
    int kr = t >> 3, nc = (t & 7) * 4;
    float4 v = *(const float4*)(in + (size_t)(k0 + kr) * N + n0 + nc);
    tile[kr][nc] = v.x; tile[kr][nc + 1] = v.y; tile[kr][nc + 2] = v.z; tile[kr][nc + 3] = v.w;
    __syncthreads();
    unsigned short o[4];
#pragma unroll
    for (int i = 0; i < 4; i++) o[i] = f2b(tile[nc + i][kr]);
    *(uint2*)(out + (size_t)(n0 + kr) * K + k0 + nc) = *(uint2*)o;
}

// ---------------- bf16 MFMA GEMM, global_load_lds + BK=64 XOR swizzle ----------------
// EPI 0: qkv fused (q/k -> qkv stride 1024 w/ fused L2-norm; v -> vt via LDS transpose, coalesced)
// EPI 1: res + gate*0.5*v (fp32 out)   EPI 2: gelu tanh-form (bf16 out)   EPI 3: clip(res+gate*v,+-10) (fp32 out)
template<int EPI, int OBF, int BM>
__global__ __launch_bounds__(256)
void gemm_bf16(const unsigned short* __restrict__ A, const unsigned short* __restrict__ BT,
               const float* __restrict__ bias, const float* __restrict__ bias_b,
               const float* __restrict__ bias_c, const float* __restrict__ res,
               void* __restrict__ Cv, unsigned short* __restrict__ vtout,
               int M, int N, int K, const float* __restrict__ gate_p)
{
    constexpr int WN = (BM == 128) ? 2 : 4;
    constexpr int WSPAN = 128 / WN;
    constexpr int NT = WSPAN / 16;
    constexpr int MT = 4;
    constexpr int ACALLS = BM / 32;
    // EPI0 needs [128][136] bf16 transpose buffer (17408 shorts); others just staging
    constexpr int SMEMSZ = (EPI == 0) ? 17408 : (BM * 64 + 128 * 64);
    __shared__ __align__(16) unsigned short SMEM[SMEMSZ];
    unsigned short* As = SMEM;
    unsigned short* Bs = SMEM + BM * 64;
    const int tid = threadIdx.x, w = tid >> 6, lane = tid & 63, quad = lane >> 4, ln = lane & 15;
    const int wm = w / WN, wn = w % WN;
    const int m0 = blockIdx.y * BM, n0 = blockIdx.x * 128;
    const int jg = (lane & 7) ^ ((lane >> 3) & 7);
    const int rb = w * 8 + (lane >> 3);
    const unsigned short* Agl = A + (size_t)(m0 + rb) * K + jg * 8;
    const unsigned short* Bgl = BT + (size_t)(n0 + rb) * K + jg * 8;

    fvec4 acc[MT][NT];
#pragma unroll
    for (int mt = 0; mt < MT; mt++)
#pragma unroll
        for (int nt = 0; nt < NT; nt++)
#pragma unroll
            for (int r = 0; r < 4; r++) acc[mt][nt][r] = 0.f;

    for (int k0 = 0; k0 < K; k0 += 64) {
        __syncthreads();
#pragma unroll
        for (int c = 0; c < ACALLS; c++)
            glds16(Agl + k0 + (size_t)c * 32 * K, As + c * 2048 + w * 512);
#pragma unroll
        for (int c = 0; c < 4; c++)
            glds16(Bgl + k0 + (size_t)c * 32 * K, Bs + c * 2048 + w * 512);
        __syncthreads();
#pragma unroll
        for (int kk = 0; kk < 2; kk++) {
            svec8 af[MT], bfr[NT];
#pragma unroll
            for (int mt = 0; mt < MT; mt++)
                af[mt] = FRAG(As, wm * 64 + mt * 16 + ln, kk * 4 + quad);
#pragma unroll
            for (int nt = 0; nt < NT; nt++)
                bfr[nt] = FRAG(Bs, wn * WSPAN + nt * 16 + ln, kk * 4 + quad);
#pragma unroll
            for (int mt = 0; mt < MT; mt++)
#pragma unroll
                for (int nt = 0; nt < NT; nt++)
                    acc[mt][nt] = mfma16(af[mt], bfr[nt], acc[mt][nt]);
        }
    }

    const float gate = (EPI == 1 || EPI == 3) ? gate_p[0] : 0.f;
    float bb[NT];
#pragma unroll
    for (int nt = 0; nt < NT; nt++) {
        int n = n0 + wn * WSPAN + nt * 16 + ln;
        if (EPI == 0) {
            int nseg = n >> 9;
            const float* bsel = nseg == 0 ? bias : (nseg == 1 ? bias_b : bias_c);
            bb[nt] = bsel[n - nseg * 512];
        } else {
            bb[nt] = bias[n];
        }
    }

    if (EPI == 0 && n0 >= 1024) {
        // ---- V path: bias + LDS transpose -> coalesced vt writes ----
        __syncthreads();                    // staging reads done; reuse SMEM
#pragma unroll
        for (int mt = 0; mt < MT; mt++) {
#pragma unroll
            for (int nt = 0; nt < NT; nt++) {
                int nl = wn * 64 + nt * 16 + ln;
                int mb = wm * 64 + mt * 16 + quad * 4;
                unsigned int lo = pk2b(acc[mt][nt][0] + bb[nt], acc[mt][nt][1] + bb[nt]);
                unsigned int hi = pk2b(acc[mt][nt][2] + bb[nt], acc[mt][nt][3] + bb[nt]);
                uint2 u; u.x = lo; u.y = hi;
                *(uint2*)(SMEM + nl * 136 + mb) = u;
            }
        }
        __syncthreads();
        int row = tid >> 1, half = (tid & 1) * 64;
        unsigned short* dst = vtout + ((size_t)((m0 >> 11) * 512 + (n0 - 1024) + row)) * T
                              + (m0 & (T - 1)) + half;
        const unsigned short* src = SMEM + row * 136 + half;
#pragma unroll
        for (int j = 0; j < 8; j++) *(uint4*)(dst + j * 8) = *(const uint4*)(src + j * 8);
        return;
    }

#pragma unroll
    for (int mt = 0; mt < MT; mt++) {
        float v[NT][4];
#pragma unroll
        for (int nt = 0; nt < NT; nt++)
#pragma unroll
            for (int r = 0; r < 4; r++) v[nt][r] = acc[mt][nt][r] + bb[nt];
        if (EPI == 0) {   // q/k: fused L2 norm over the 64-wide head span
#pragma unroll
            for (int r = 0; r < 4; r++) {
                float s = 0.f;
#pragma unroll
                for (int nt = 0; nt < NT; nt++) s += v[nt][r] * v[nt][r];
                s += __shfl_xor(s, 1); s += __shfl_xor(s, 2);
                s += __shfl_xor(s, 4); s += __shfl_xor(s, 8);
                float rs = 1.f / fmaxf(sqrtf(s), 1e-8f);
#pragma unroll
                for (int nt = 0; nt < NT; nt++) v[nt][r] *= rs;
            }
        }
#pragma unroll
        for (int nt = 0; nt < NT; nt++) {
            int n = n0 + wn * WSPAN + nt * 16 + ln;
#pragma unroll
            for (int r = 0; r < 4; r++) {
                int m = m0 + wm * 64 + mt * 16 + quad * 4 + r;
                float val = v[nt][r];
                if (EPI == 0) {
                    ((unsigned short*)Cv)[(size_t)m * QS2 + n] = f2b(val);
                } else {
                    size_t off = (size_t)m * N + n;
                    if (EPI == 1) val = res[off] + gate * 0.5f * val;
                    else if (EPI == 2) {
                        float u = val;
                        float z = 0.7978845608028654f * fmaf(0.044715f * u, u * u, u);
                        float e = __builtin_amdgcn_exp2f(z * 2.8853900817779268f);
                        float rr = __builtin_amdgcn_rcpf(e + 1.f);
                        val = u * (1.f - rr);
                    }
                    else if (EPI == 3) val = fminf(fmaxf(res[off] + gate * val, -10.f), 10.f);
                    if (OBF) ((unsigned short*)Cv)[off] = f2b(val);
                    else ((float*)Cv)[off] = val;
                }
            }
        }
    }
}

// ---------------- paired flash attention: S^T operand order, packed P stores, l via MFMA ----------------
__device__ __forceinline__ void attn_step(
    const unsigned short* Q, unsigned short* Ps, const unsigned short* Ks, const unsigned short* Vt,
    bool diag, fvec4 (&oacc)[4], fvec4& lacc, int w, int quad, int ln)
{
    constexpr short BONE = (short)0x3F80;     // bf16 1.0
    const svec8 ONES8 = {BONE, BONE, BONE, BONE, BONE, BONE, BONE, BONE};
    // S^T = K·Q^T: D[m = s-tile rows][n = q col = ln]
    svec8 qf0 = FRAG(Q, w * 16 + ln, quad);
    svec8 qf1 = FRAG(Q, w * 16 + ln, 4 + quad);
    const int qrow = w * 16 + ln;             // this lane's q row (as P row)
#pragma unroll
    for (int nt = 0; nt < 4; nt++) {
        fvec4 z; z[0] = z[1] = z[2] = z[3] = 0.f;
        z = mfma16(FRAG(Ks, nt * 16 + ln, quad), qf0, z);
        z = mfma16(FRAG(Ks, nt * 16 + ln, 4 + quad), qf1, z);
        const int sbase = nt * 16 + quad * 4;
        float p[4];
#pragma unroll
        for (int r = 0; r < 4; r++) {
            // e^y, y in [-0.059,0.059]: quadratic Taylor, err < 4e-5 << bf16 P quantization
            float y = z[r] * K2;
            float pv = fmaf(y, fmaf(y, 0.5f, 1.f), 1.f);
            if (diag && (sbase + r > qrow)) pv = 0.f;
            p[r] = pv;
        }
        uint2 u; u.x = pk2b(p[0], p[1]); u.y = pk2b(p[2], p[3]);
        int chunk = sbase >> 3, off = sbase & 7;
        *(uint2*)(Ps + ((qrow << 6) | ((chunk ^ (qrow & 7)) << 3) | off)) = u;
    }
#pragma unroll
    for (int ks = 0; ks < 2; ks++) {
        svec8 pa = FRAG(Ps, w * 16 + ln, ks * 4 + quad);
        lacc = mfma16(pa, ONES8, lacc);       // row sums of (quantized) P
#pragma unroll
        for (int nt = 0; nt < 4; nt++)
            oacc[nt] = mfma16(pa, FRAG(Vt, nt * 16 + ln, ks * 4 + quad), oacc[nt]);
    }
}

__global__ __launch_bounds__(256)
void attn_pair_kernel(const unsigned short* __restrict__ qkv, const unsigned short* __restrict__ vt,
                      unsigned short* __restrict__ o)
{
    __shared__ __align__(16) unsigned short QA[4096], QB[4096];
    __shared__ __align__(16) unsigned short K0[4096], V0[4096], K1[4096], V1[4096];
    __shared__ __align__(16) unsigned short Ps[4096];
    const int p = blockIdx.x, bh = blockIdx.y, b = bh >> 3, hh = bh & 7;
    const int qtA = p, qtB = 31 - p, nst = 32 - p;
    const int tid = threadIdx.x, w = tid >> 6, lane = tid & 63, quad = lane >> 4, ln = lane & 15;
    const int rl = lane >> 3, sl = lane & 7, jgz = sl ^ rl;
    const int w8 = w * 8;
    const int grow = w8 + rl;
    const unsigned short* qrow_p = qkv + ((size_t)(b * T) + grow) * QS2 + hh * 64 + jgz * 8;
    const unsigned short* krow_p = qrow_p + 512;
    const unsigned short* vrow_p = vt + ((size_t)(bh * 64) + grow) * T + jgz * 8;

    glds16(qrow_p + (size_t)(qtA * 64) * QS2, QA + w8 * 64);
    glds16(qrow_p + (size_t)(qtA * 64 + 32) * QS2, QA + (w8 + 32) * 64);
    glds16(qrow_p + (size_t)(qtB * 64) * QS2, QB + w8 * 64);
    glds16(qrow_p + (size_t)(qtB * 64 + 32) * QS2, QB + (w8 + 32) * 64);

    fvec4 oA[4], oB[4], lAv, lBv;
#pragma unroll
    for (int r = 0; r < 4; r++) { lAv[r] = 0.f; lBv[r] = 0.f; }
#pragma unroll
    for (int nt = 0; nt < 4; nt++)
#pragma unroll
        for (int r = 0; r < 4; r++) { oA[nt][r] = 0.f; oB[nt][r] = 0.f; }

    const int Nph = (nst + 1) >> 1;
    for (int ph = 0; ph < Nph; ph++) {
        const int s0 = 2 * ph, s1 = 2 * ph + 1;
        __syncthreads();   // all reads of K0/V0/K1/V1 from previous phase complete
        glds16(krow_p + (size_t)(s0 * 64) * QS2, K0 + w8 * 64);
        glds16(krow_p + (size_t)(s0 * 64 + 32) * QS2, K0 + (w8 + 32) * 64);
        glds16(vrow_p + s0 * 64, V0 + w8 * 64);
        glds16(vrow_p + (size_t)32 * T + s0 * 64, V0 + (w8 + 32) * 64);
        if (s1 < nst) {
            glds16(krow_p + (size_t)(s1 * 64) * QS2, K1 + w8 * 64);
            glds16(krow_p + (size_t)(s1 * 64 + 32) * QS2, K1 + (w8 + 32) * 64);
            glds16(vrow_p + s1 * 64, V1 + w8 * 64);
            glds16(vrow_p + (size_t)32 * T + s1 * 64, V1 + (w8 + 32) * 64);
        }
        __syncthreads();   // vmcnt drained: staged data visible
        attn_step(QB, Ps, K0, V0, s0 == nst - 1, oB, lBv, w, quad, ln);
        if (s0 <= p) attn_step(QA, Ps, K0, V0, s0 == p, oA, lAv, w, quad, ln);
        if (s1 < nst) {
            attn_step(QB, Ps, K1, V1, s1 == nst - 1, oB, lBv, w, quad, ln);
            if (s1 <= p) attn_step(QA, Ps, K1, V1, s1 == p, oA, lAv, w, quad, ln);
        }
    }

    unsigned short* ogA = o + (size_t)(b * T + qtA * 64 + w * 16 + quad * 4) * D + hh * 64;
    unsigned short* ogB = o + (size_t)(b * T + qtB * 64 + w * 16 + quad * 4) * D + hh * 64;
#pragma unroll
    for (int r = 0; r < 4; r++) {
        float ia = 1.f / lAv[r], ib = 1.f / lBv[r];
#pragma unroll
        for (int nt = 0; nt < 4; nt++) {
            ogA[(size_t)r * D + nt * 16 + ln] = f2b(oA[nt][r] * ia);
            ogB[(size_t)r * D + nt * 16 + ln] = f2b(oB[nt][r] * ib);
        }
    }
}

// ---------------- masked-mean pool partials ----------------
__global__ __launch_bounds__(256)
void pool_kernel(const float* __restrict__ hn, const float* __restrict__ x, float* __restrict__ part)
{
    int b = blockIdx.x, ch = blockIdx.y, tid = threadIdx.x;
    int t0 = ch * 128;
    float s0 = 0.f, s1 = 0.f, cnt = 0.f;
    for (int tt = 0; tt < 128; tt++) {
        int t = t0 + tt;
        float xv = x[b * T + t];
        float m = (xv == -1.0f) ? 0.f : 1.f;
        cnt += m;
        const float* r = hn + ((size_t)(b * T + t)) * D;
        s0 += r[tid] * m;
        s1 += r[tid + 256] * m;
    }
    float* pr = part + (size_t)(b * 16 + ch) * 513;
    pr[tid] = s0; pr[tid + 256] = s1;
    if (tid == 0) pr[512] = cnt;
}

// ---------------- heads ----------------
__global__ __launch_bounds__(64)
void head_kernel(const float* __restrict__ part,
                 const float* __restrict__ bh_g, const float* __restrict__ bh_bl,
                 const float* __restrict__ ah_g, const float* __restrict__ ah_bl,
                 const float* __restrict__ ch_g, const float* __restrict__ ch_bl,
                 const float* __restrict__ bh_w, const float* __restrict__ bh_b2,
                 const float* __restrict__ ah_w, const float* __restrict__ ah_b2,
                 const float* __restrict__ ch_w, const float* __restrict__ ch_b2,
                 float* __restrict__ out)
{
    int b = blockIdx.x, lane = threadIdx.x;
    float cnt = 0.f;
    for (int c = 0; c < 16; c++) cnt += part[(size_t)(b * 16 + c) * 513 + 512];
    float denom = fmaxf(cnt, 1.f);
    float md[8];
    float s = 0.f, s2 = 0.f;
#pragma unroll
    for (int j = 0; j < 8; j++) {
        int d = j * 64 + lane;
        float acc = 0.f;
        for (int c = 0; c < 16; c++) acc += part[(size_t)(b * 16 + c) * 513 + d];
        md[j] = acc / denom;
        s += md[j]; s2 += md[j] * md[j];
    }
    s = wave_red_sum(s); s2 = wave_red_sum(s2);
    float mu = s * (1.f / 512.f);
    float var = s2 * (1.f / 512.f) - mu * mu;
    float rstd = 1.f / sqrtf(var + 1e-5f);
    float a0 = 0.f, a1 = 0.f, a2 = 0.f, a3 = 0.f;
#pragma unroll
    for (int j = 0; j < 8; j++) {
        int d = j * 64 + lane;
        float z = (md[j] - mu) * rstd;
        float zb = z * bh_g[d] + bh_bl[d];
        a0 += zb * bh_w[d * 2 + 0];
        a1 += zb * bh_w[d * 2 + 1];
        a2 += (z * ah_g[d] + ah_bl[d]) * ah_w[d];
        a3 += (z * ch_g[d] + ch_bl[d]) * ch_w[d];
    }
    a0 = wave_red_sum(a0); a1 = wave_red_sum(a1);
    a2 = wave_red_sum(a2); a3 = wave_red_sum(a3);
    if (lane == 0) {
        out[b * 4 + 0] = a0 + bh_b2[0];
        out[b * 4 + 1] = a1 + bh_b2[1];
        out[b * 4 + 2] = a2 + ah_b2[0];
        float t3 = a3 + ch_b2[0];
        out[b * 4 + 3] = 1.f / (1.f + expf(-t3));
    }
}

// ---------------- launch ----------------
extern "C" void kernel_launch(void* const* d_in, const int* in_sizes, int n_in,
                              void* d_out, int out_size, void* d_ws, size_t ws_size,
                              hipStream_t stream)
{
    const float* x      = (const float*)d_in[0];
    const float* ip_w   = (const float*)d_in[1];
    const float* ip_b   = (const float*)d_in[2];
    const float* ip_ln_g= (const float*)d_in[3];
    const float* ip_ln_b= (const float*)d_in[4];
    const float* pos    = (const float*)d_in[5];
    const float* pad_tok= (const float*)d_in[6];
    const float* Wq = (const float*)d_in[7];  const float* bq = (const float*)d_in[8];
    const float* Wk = (const float*)d_in[9];  const float* bk = (const float*)d_in[10];
    const float* Wv = (const float*)d_in[11]; const float* bv = (const float*)d_in[12];
    const float* Wo = (const float*)d_in[13]; const float* bo = (const float*)d_in[14];
    const float* ln1_g = (const float*)d_in[15]; const float* ln1_b = (const float*)d_in[16];
    const float* ln2_g = (const float*)d_in[17]; const float* ln2_b = (const float*)d_in[18];
    const float* W1 = (const float*)d_in[19]; const float* b1 = (const float*)d_in[20];
    const float* W2 = (const float*)d_in[21]; const float* b2 = (const float*)d_in[22];
    const float* gate1 = (const float*)d_in[23]; const float* gate2 = (const float*)d_in[24];
    const float* fn_g = (const float*)d_in[25]; const float* fn_b = (const float*)d_in[26];
    const float* bh_g  = (const float*)d_in[27]; const float* bh_bl = (const float*)d_in[28];
    const float* ah_g  = (const float*)d_in[29]; const float* ah_bl = (const float*)d_in[30];
    const float* ch_g  = (const float*)d_in[31]; const float* ch_bl = (const float*)d_in[32];
    const float* bh_w  = (const float*)d_in[33]; const float* bh_b2 = (const float*)d_in[34];
    const float* ah_w  = (const float*)d_in[35]; const float* ah_b2 = (const float*)d_in[36];
    const float* ch_w  = (const float*)d_in[37]; const float* ch_b2 = (const float*)d_in[38];

    char* ws = (char*)d_ws;
    float*          h     = (float*)ws;                       // 16 MB fp32 [8192][512]
    unsigned short* act_b = (unsigned short*)(ws + 16777216); // 8 MB bf16 [8192][512]
    unsigned short* qkv   = (unsigned short*)(ws + 25165824); // 16 MB bf16 [8192][1024] (q|k)
    unsigned short* mid_b = (unsigned short*)(ws + 41943040); // 32 MB bf16 [8192][2048]
    float*          xn_f  = (float*)(ws + 41943040);          // 16 MB alias (final LN only)
    unsigned short* wT    = (unsigned short*)(ws + 75497472); // 6 MB per-layer transposed weights
    unsigned short* vt    = (unsigned short*)(ws + 81788928); // 8 MB bf16 [4*512][2048]
    float*          part  = (float*)(ws + 90177536);
    float*          out   = (float*)d_out;

    unsigned short* wqT = wT;             // [1536][512] (q,k,v contiguous)
    unsigned short* wkT = wT + 262144;
    unsigned short* wvT = wT + 524288;
    unsigned short* woT = wT + 786432;
    unsigned short* w1T = wT + 1048576;   // [2048][512]
    unsigned short* w2T = wT + 2097152;   // [512][2048]

    embed_kernel<<<dim3(Bsz * T), dim3(64), 0, stream>>>(x, ip_w, ip_b, ip_ln_g, ip_ln_b, pos, pad_tok, h);

    for (int i = 0; i < Lnum; i++) {
        const size_t dd = (size_t)i * D * D;
        const size_t df = (size_t)i * D * DFF;
        wconv_kernel<<<dim3(3072), dim3(256), 0, stream>>>(Wq + dd, Wk + dd, Wv + dd, Wo + dd,
                                                           W1 + df, W2 + df,
                                                           wqT, wkT, wvT, woT, w1T, w2T);
        ln_bf16_kernel<<<dim3(Bsz * T / 4), dim3(256), 0, stream>>>(h, act_b, ln1_g + i * D, ln1_b + i * D);
        gemm_bf16<0, 1, 128><<<dim3(12, 64), dim3(256), 0, stream>>>(act_b, wqT, bq + i * D, bk + i * D, bv + i * D,
                                                                     nullptr, qkv, vt, Bsz * T, 1536, D, nullptr);
        attn_pair_kernel<<<dim3(16, 32), dim3(256), 0, stream>>>(qkv, vt, act_b);
        gemm_bf16<1, 0, 64><<<dim3(4, 128), dim3(256), 0, stream>>>(act_b, woT, bo + i * D, nullptr, nullptr,
                                                                    h, h, nullptr, Bsz * T, D, D, gate1 + i);
        ln_bf16_kernel<<<dim3(Bsz * T / 4), dim3(256), 0, stream>>>(h, act_b, ln2_g + i * D, ln2_b + i * D);
        gemm_bf16<2, 1, 128><<<dim3(16, 64), dim3(256), 0, stream>>>(act_b, w1T, b1 + i * DFF, nullptr, nullptr,
                                                                     nullptr, mid_b, nullptr, Bsz * T, DFF, D, nullptr);
        gemm_bf16<3, 0, 64><<<dim3(4, 128), dim3(256), 0, stream>>>(mid_b, w2T, b2 + i * D, nullptr, nullptr,
                                                                    h, h, nullptr, Bsz * T, D, DFF, gate2 + i);
    }

    ln_kernel<<<dim3(Bsz * T / 4), dim3(256), 0, stream>>>(h, xn_f, fn_g, fn_b);
    pool_kernel<<<dim3(Bsz, 16), dim3(256), 0, stream>>>(xn_f, x, part);
    head_kernel<<<dim3(Bsz), dim3(64), 0, stream>>>(part, bh_g, bh_bl, ah_g, ah_bl, ch_g, ch_bl,
                                                    bh_w, bh_b2, ah_w, ah_b2, ch_w, ch_b2, out);
}

// Round 6
// 1133.825 us; speedup vs baseline: 6.8364x; 1.0828x over previous
//
#include <hip/hip_runtime.h>
#include <hip/hip_bf16.h>
#include <math.h>

// ---------------- constants ----------------
constexpr int Bsz = 4, T = 2048, D = 512, H = 8, Lnum = 6, DFF = 2048, DK = 64;
constexpr int QS2 = 1024;                       // qkv row stride (q at 0, k at 512; v goes to vt)
constexpr float K2 = 0.08838834764831845f / 1.5f;  // softmax exponent scale (folded into q)

typedef __attribute__((ext_vector_type(8))) short svec8;   // 8 bf16 (4 VGPRs)
typedef __attribute__((ext_vector_type(4))) float fvec4;   // 4 fp32 acc

__device__ __forceinline__ fvec4 mfma16(svec8 a, svec8 b, fvec4 c) {
    return __builtin_amdgcn_mfma_f32_16x16x32_bf16(a, b, c, 0, 0, 0);
}
__device__ __forceinline__ unsigned short f2b(float f) {
    unsigned int u = __float_as_uint(f);
    u += 0x7fffu + ((u >> 16) & 1u);
    return (unsigned short)(u >> 16);
}
__device__ __forceinline__ unsigned int pk2b(float a, float b) {
    __hip_bfloat162 h = __float22bfloat162_rn(float2{a, b});
    return *(unsigned int*)&h;
}
__device__ __forceinline__ float wave_red_sum(float v) {
    for (int o = 32; o > 0; o >>= 1) v += __shfl_down(v, o, 64);
    return __shfl(v, 0, 64);
}
// async global->LDS, 16B per lane; lds base must be wave-uniform (HW adds lane*16)
__device__ __forceinline__ void glds16(const unsigned short* g, unsigned short* l) {
    __builtin_amdgcn_global_load_lds(
        (const __attribute__((address_space(1))) unsigned int*)g,
        (__attribute__((address_space(3))) unsigned int*)l, 16, 0, 0);
}
// swizzled-tile fragment read: 64-wide rows, chunk kq of row r at slot kq^(r&7)
#define FRAG(buf, row, kq) (*(const svec8*)((buf) + (((row) << 6) | ((((kq) ^ ((row) & 7))) << 3))))

// ---------------- embed (fp32 h) ----------------
__global__ __launch_bounds__(64)
void embed_kernel(const float* __restrict__ x, const float* __restrict__ ip_w,
                  const float* __restrict__ ip_b, const float* __restrict__ g,
                  const float* __restrict__ bta, const float* __restrict__ pos,
                  const float* __restrict__ pad_tok, float* __restrict__ h)
{
    int row = blockIdx.x;
    int t = row & (T - 1);
    int lane = threadIdx.x;
    float xv = x[row];
    float xc = fminf(fmaxf(xv, -10.f), 10.f);
    bool pad = (xc == -1.0f);
    float pre[8];
    float s = 0.f, s2 = 0.f;
#pragma unroll
    for (int j = 0; j < 8; j++) {
        int d = j * 64 + lane;
        float p = xc * ip_w[d] + ip_b[d];
        pre[j] = p; s += p; s2 += p * p;
    }
    s = wave_red_sum(s); s2 = wave_red_sum(s2);
    float m = s * (1.f / 512.f);
    float var = s2 * (1.f / 512.f) - m * m;
    float rstd = 1.f / sqrtf(var + 1e-5f);
#pragma unroll
    for (int j = 0; j < 8; j++) {
        int d = j * 64 + lane;
        float hv = (pre[j] - m) * rstd * g[d] + bta[d] + 0.1f * pos[(size_t)t * D + d];
        if (pad) hv = pad_tok[d];
        h[(size_t)row * D + d] = hv;
    }
}

// ---------------- LayerNorm fp32 -> fp32 (final), 4 rows/block ----------------
__global__ __launch_bounds__(256)
void ln_kernel(const float* __restrict__ in, float* __restrict__ out,
               const float* __restrict__ g, const float* __restrict__ b)
{
    int row = blockIdx.x * 4 + (threadIdx.x >> 6);
    int lane = threadIdx.x & 63;
    const float* r = in + (size_t)row * D;
    float4 v0 = ((const float4*)r)[lane];
    float4 v1 = ((const float4*)r)[lane + 64];
    float s = v0.x + v0.y + v0.z + v0.w + v1.x + v1.y + v1.z + v1.w;
    float s2 = v0.x*v0.x + v0.y*v0.y + v0.z*v0.z + v0.w*v0.w
             + v1.x*v1.x + v1.y*v1.y + v1.z*v1.z + v1.w*v1.w;
    s = wave_red_sum(s); s2 = wave_red_sum(s2);
    float m = s * (1.f / 512.f);
    float var = s2 * (1.f / 512.f) - m * m;
    float rstd = 1.f / sqrtf(var + 1e-5f);
    float4 g0 = ((const float4*)g)[lane], g1 = ((const float4*)g)[lane + 64];
    float4 b0 = ((const float4*)b)[lane], b1 = ((const float4*)b)[lane + 64];
    float4 o0, o1;
    o0.x = (v0.x - m) * rstd * g0.x + b0.x; o0.y = (v0.y - m) * rstd * g0.y + b0.y;
    o0.z = (v0.z - m) * rstd * g0.z + b0.z; o0.w = (v0.w - m) * rstd * g0.w + b0.w;
    o1.x = (v1.x - m) * rstd * g1.x + b1.x; o1.y = (v1.y - m) * rstd * g1.y + b1.y;
    o1.z = (v1.z - m) * rstd * g1.z + b1.z; o1.w = (v1.w - m) * rstd * g1.w + b1.w;
    ((float4*)(out + (size_t)row * D))[lane] = o0;
    ((float4*)(out + (size_t)row * D))[lane + 64] = o1;
}

// ---------------- LayerNorm fp32 -> bf16, 4 rows/block ----------------
__global__ __launch_bounds__(256)
void ln_bf16_kernel(const float* __restrict__ in, unsigned short* __restrict__ out,
                    const float* __restrict__ g, const float* __restrict__ b)
{
    int row = blockIdx.x * 4 + (threadIdx.x >> 6);
    int lane = threadIdx.x & 63;
    const float* r = in + (size_t)row * D;
    float4 v0 = ((const float4*)r)[lane];
    float4 v1 = ((const float4*)r)[lane + 64];
    float s = v0.x + v0.y + v0.z + v0.w + v1.x + v1.y + v1.z + v1.w;
    float s2 = v0.x*v0.x + v0.y*v0.y + v0.z*v0.z + v0.w*v0.w
             + v1.x*v1.x + v1.y*v1.y + v1.z*v1.z + v1.w*v1.w;
    s = wave_red_sum(s); s2 = wave_red_sum(s2);
    float m = s * (1.f / 512.f);
    float var = s2 * (1.f / 512.f) - m * m;
    float rstd = 1.f / sqrtf(var + 1e-5f);
    float4 g0 = ((const float4*)g)[lane], g1 = ((const float4*)g)[lane + 64];
    float4 b0 = ((const float4*)b)[lane], b1 = ((const float4*)b)[lane + 64];
    unsigned short o0[4], o1[4];
    o0[0] = f2b((v0.x - m) * rstd * g0.x + b0.x); o0[1] = f2b((v0.y - m) * rstd * g0.y + b0.y);
    o0[2] = f2b((v0.z - m) * rstd * g0.z + b0.z); o0[3] = f2b((v0.w - m) * rstd * g0.w + b0.w);
    o1[0] = f2b((v1.x - m) * rstd * g1.x + b1.x); o1[1] = f2b((v1.y - m) * rstd * g1.y + b1.y);
    o1[2] = f2b((v1.z - m) * rstd * g1.z + b1.z); o1[3] = f2b((v1.w - m) * rstd * g1.w + b1.w);
    *(uint2*)(out + (size_t)row * D + lane * 4) = *(uint2*)o0;
    *(uint2*)(out + (size_t)row * D + 256 + lane * 4) = *(uint2*)o1;
}

// ---------------- weight transpose + cast: fp32 [K][N] -> bf16 [N][K], per layer ----------------
__global__ __launch_bounds__(256)
void wconv_kernel(const float* __restrict__ wq, const float* __restrict__ wk,
                  const float* __restrict__ wv, const float* __restrict__ wo,
                  const float* __restrict__ w1, const float* __restrict__ w2,
                  unsigned short* __restrict__ oq, unsigned short* __restrict__ ok,
                  unsigned short* __restrict__ ov, unsigned short* __restrict__ oo,
                  unsigned short* __restrict__ o1, unsigned short* __restrict__ o2)
{
    __shared__ float tile[32][33];
    int bid = blockIdx.x;
    const float* in; unsigned short* out; int K, N, kt, nt;
    if (bid < 1024) {
        int sel = bid >> 8, loc = bid & 255;
        in  = sel == 0 ? wq : sel == 1 ? wk : sel == 2 ? wv : wo;
        out = sel == 0 ? oq : sel == 1 ? ok : sel == 2 ? ov : oo;
        K = 512; N = 512; kt = loc >> 4; nt = loc & 15;
    } else if (bid < 2048) {
        int loc = bid - 1024; in = w1; out = o1; K = 512; N = 2048; kt = loc >> 6; nt = loc & 63;
    } else {
        int loc = bid - 2048; in = w2; out = o2; K = 2048; N = 512; kt = loc >> 4; nt = loc & 15;
    }
    int k0 = kt * 32, n0 = nt * 32;
    int t = threadIdx.x;
    int kr = t >> 3, nc = (t & 7) * 4;
    float4 v = *(const float4*)(in + (size_t)(k0 + kr) * N + n0 + nc);
    tile[kr][nc] = v.x; tile[kr][nc + 1] = v.y; tile[kr][nc + 2] = v.z; tile[kr][nc + 3] = v.w;
    __syncthreads();
    unsigned short o[4];
#pragma unroll
    for (int i = 0; i < 4; i++) o[i] = f2b(tile[nc + i][kr]);
    *(uint2*)(out + (size_t)(n0 + kr) * K + k0 + nc) = *(uint2*)o;
}

// ---------------- bf16 MFMA GEMM, global_load_lds + BK=64 XOR swizzle ----------------
// Grid: (M/BM, N/128) — m-tiles on x so same-weight blocks land on one XCD.
// EPI 0: qkv fused (q (pre-scaled by K2) / k -> qkv w/ L2-norm; v -> vt via LDS transpose)
// EPI 1: res + gate*0.5*v (fp32 out)   EPI 2: gelu tanh-form (bf16 out)   EPI 3: clip(res+gate*v,+-10) (fp32 out)
template<int EPI, int OBF, int BM>
__global__ __launch_bounds__(256)
void gemm_bf16(const unsigned short* __restrict__ A, const unsigned short* __restrict__ BT,
               const float* __restrict__ bias, const float* __restrict__ bias_b,
               const float* __restrict__ bias_c, const float* __restrict__ res,
               void* __restrict__ Cv, unsigned short* __restrict__ vtout,
               int M, int N, int K, const float* __restrict__ gate_p)
{
    constexpr int WN = (BM == 128) ? 2 : 4;
    constexpr int WSPAN = 128 / WN;
    constexpr int NT = WSPAN / 16;
    constexpr int MT = 4;
    constexpr int ACALLS = BM / 32;
    constexpr int SMEMSZ = (EPI == 0) ? 17408 : (BM * 64 + 128 * 64);
    __shared__ __align__(16) unsigned short SMEM[SMEMSZ];
    unsigned short* As = SMEM;
    unsigned short* Bs = SMEM + BM * 64;
    const int tid = threadIdx.x, w = tid >> 6, lane = tid & 63, quad = lane >> 4, ln = lane & 15;
    const int wm = w / WN, wn = w % WN;
    const int m0 = blockIdx.x * BM, n0 = blockIdx.y * 128;
    const int jg = (lane & 7) ^ ((lane >> 3) & 7);
    const int rb = w * 8 + (lane >> 3);
    const unsigned short* Agl = A + (size_t)(m0 + rb) * K + jg * 8;
    const unsigned short* Bgl = BT + (size_t)(n0 + rb) * K + jg * 8;

    fvec4 acc[MT][NT];
#pragma unroll
    for (int mt = 0; mt < MT; mt++)
#pragma unroll
        for (int nt = 0; nt < NT; nt++)
#pragma unroll
            for (int r = 0; r < 4; r++) acc[mt][nt][r] = 0.f;

    for (int k0 = 0; k0 < K; k0 += 64) {
        __syncthreads();
#pragma unroll
        for (int c = 0; c < ACALLS; c++)
            glds16(Agl + k0 + (size_t)c * 32 * K, As + c * 2048 + w * 512);
#pragma unroll
        for (int c = 0; c < 4; c++)
            glds16(Bgl + k0 + (size_t)c * 32 * K, Bs + c * 2048 + w * 512);
        __syncthreads();
#pragma unroll
        for (int kk = 0; kk < 2; kk++) {
            svec8 af[MT], bfr[NT];
#pragma unroll
            for (int mt = 0; mt < MT; mt++)
                af[mt] = FRAG(As, wm * 64 + mt * 16 + ln, kk * 4 + quad);
#pragma unroll
            for (int nt = 0; nt < NT; nt++)
                bfr[nt] = FRAG(Bs, wn * WSPAN + nt * 16 + ln, kk * 4 + quad);
#pragma unroll
            for (int mt = 0; mt < MT; mt++)
#pragma unroll
                for (int nt = 0; nt < NT; nt++)
                    acc[mt][nt] = mfma16(af[mt], bfr[nt], acc[mt][nt]);
        }
    }

    const float gate = (EPI == 1 || EPI == 3) ? gate_p[0] : 0.f;
    float bb[NT];
#pragma unroll
    for (int nt = 0; nt < NT; nt++) {
        int n = n0 + wn * WSPAN + nt * 16 + ln;
        if (EPI == 0) {
            int nseg = n >> 9;
            const float* bsel = nseg == 0 ? bias : (nseg == 1 ? bias_b : bias_c);
            bb[nt] = bsel[n - nseg * 512];
        } else {
            bb[nt] = bias[n];
        }
    }

    if (EPI == 0 && n0 >= 1024) {
        // ---- V path: bias + LDS transpose -> coalesced vt writes ----
        __syncthreads();                    // staging reads done; reuse SMEM
#pragma unroll
        for (int mt = 0; mt < MT; mt++) {
#pragma unroll
            for (int nt = 0; nt < NT; nt++) {
                int nl = wn * 64 + nt * 16 + ln;
                int mb = wm * 64 + mt * 16 + quad * 4;
                unsigned int lo = pk2b(acc[mt][nt][0] + bb[nt], acc[mt][nt][1] + bb[nt]);
                unsigned int hi = pk2b(acc[mt][nt][2] + bb[nt], acc[mt][nt][3] + bb[nt]);
                uint2 u; u.x = lo; u.y = hi;
                *(uint2*)(SMEM + nl * 136 + mb) = u;
            }
        }
        __syncthreads();
        int row = tid >> 1, half = (tid & 1) * 64;
        unsigned short* dst = vtout + ((size_t)((m0 >> 11) * 512 + (n0 - 1024) + row)) * T
                              + (m0 & (T - 1)) + half;
        const unsigned short* src = SMEM + row * 136 + half;
#pragma unroll
        for (int j = 0; j < 8; j++) *(uint4*)(dst + j * 8) = *(const uint4*)(src + j * 8);
        return;
    }

#pragma unroll
    for (int mt = 0; mt < MT; mt++) {
        float v[NT][4];
#pragma unroll
        for (int nt = 0; nt < NT; nt++)
#pragma unroll
            for (int r = 0; r < 4; r++) v[nt][r] = acc[mt][nt][r] + bb[nt];
        if (EPI == 0) {   // q/k: fused L2 norm; q additionally pre-scaled by K2
            const float fac = ((n0 + wn * WSPAN) < 512) ? K2 : 1.f;
#pragma unroll
            for (int r = 0; r < 4; r++) {
                float s = 0.f;
#pragma unroll
                for (int nt = 0; nt < NT; nt++) s += v[nt][r] * v[nt][r];
                s += __shfl_xor(s, 1); s += __shfl_xor(s, 2);
                s += __shfl_xor(s, 4); s += __shfl_xor(s, 8);
                float rs = fac / fmaxf(sqrtf(s), 1e-8f);
#pragma unroll
                for (int nt = 0; nt < NT; nt++) v[nt][r] *= rs;
            }
        }
#pragma unroll
        for (int nt = 0; nt < NT; nt++) {
            int n = n0 + wn * WSPAN + nt * 16 + ln;
#pragma unroll
            for (int r = 0; r < 4; r++) {
                int m = m0 + wm * 64 + mt * 16 + quad * 4 + r;
                float val = v[nt][r];
                if (EPI == 0) {
                    ((unsigned short*)Cv)[(size_t)m * QS2 + n] = f2b(val);
                } else {
                    size_t off = (size_t)m * N + n;
                    if (EPI == 1) val = res[off] + gate * 0.5f * val;
                    else if (EPI == 2) {
                        float u = val;
                        float z = 0.7978845608028654f * fmaf(0.044715f * u, u * u, u);
                        float e = __builtin_amdgcn_exp2f(z * 2.8853900817779268f);
                        float rr = __builtin_amdgcn_rcpf(e + 1.f);
                        val = u * (1.f - rr);
                    }
                    else if (EPI == 3) val = fminf(fmaxf(res[off] + gate * val, -10.f), 10.f);
                    if (OBF) ((unsigned short*)Cv)[off] = f2b(val);
                    else ((float*)Cv)[off] = val;
                }
            }
        }
    }
}

// ---------------- paired flash attention: S^T order, packed P stores, l via MFMA, DIAG templated ----------------
template<bool DIAG>
__device__ __forceinline__ void attn_step(
    const unsigned short* Q, unsigned short* Ps, const unsigned short* Ks, const unsigned short* Vt,
    fvec4 (&oacc)[4], fvec4& lacc, int w, int quad, int ln)
{
    constexpr short BONE = (short)0x3F80;     // bf16 1.0
    const svec8 ONES8 = {BONE, BONE, BONE, BONE, BONE, BONE, BONE, BONE};
    // S^T = K·Q^T (q pre-scaled by K2): D[m = s rows][n = q col = ln]
    svec8 qf0 = FRAG(Q, w * 16 + ln, quad);
    svec8 qf1 = FRAG(Q, w * 16 + ln, 4 + quad);
    const int qrow = w * 16 + ln;             // this lane's q row (as P row)
#pragma unroll
    for (int nt = 0; nt < 4; nt++) {
        fvec4 z; z[0] = z[1] = z[2] = z[3] = 0.f;
        z = mfma16(FRAG(Ks, nt * 16 + ln, quad), qf0, z);
        z = mfma16(FRAG(Ks, nt * 16 + ln, 4 + quad), qf1, z);
        const int sbase = nt * 16 + quad * 4;
        float p[4];
#pragma unroll
        for (int r = 0; r < 4; r++) {
            // e^y, y in [-0.059,0.059]: quadratic Taylor, err < 4e-5 << bf16 P quantization
            float y = z[r];
            float pv = fmaf(y, fmaf(y, 0.5f, 1.f), 1.f);
            if (DIAG && (sbase + r > qrow)) pv = 0.f;
            p[r] = pv;
        }
        uint2 u; u.x = pk2b(p[0], p[1]); u.y = pk2b(p[2], p[3]);
        int chunk = sbase >> 3, off = sbase & 7;
        *(uint2*)(Ps + ((qrow << 6) | ((chunk ^ (qrow & 7)) << 3) | off)) = u;
    }
#pragma unroll
    for (int ks = 0; ks < 2; ks++) {
        svec8 pa = FRAG(Ps, w * 16 + ln, ks * 4 + quad);
        lacc = mfma16(pa, ONES8, lacc);       // row sums of (quantized) P
#pragma unroll
        for (int nt = 0; nt < 4; nt++)
            oacc[nt] = mfma16(pa, FRAG(Vt, nt * 16 + ln, ks * 4 + quad), oacc[nt]);
    }
}

__global__ __launch_bounds__(256)
void attn_pair_kernel(const unsigned short* __restrict__ qkv, const unsigned short* __restrict__ vt,
                      unsigned short* __restrict__ o)
{
    __shared__ __align__(16) unsigned short QA[4096], QB[4096];
    __shared__ __align__(16) unsigned short K0[4096], V0[4096], K1[4096], V1[4096];
    __shared__ __align__(16) unsigned short Ps[4096];
    // XCD-aware decode: blocks with the same (id & 7) share an XCD (round-robin dispatch);
    // give each XCD 4 heads -> K/V working set ~4 MB = one XCD L2.
    const int fid = blockIdx.x;
    const int xcd = fid & 7, slot = fid >> 3;
    const int bh = xcd * 4 + (slot & 3);
    const int p = slot >> 2;
    const int b = bh >> 3, hh = bh & 7;
    const int qtA = p, qtB = 31 - p, nst = 32 - p;
    const int tid = threadIdx.x, w = tid >> 6, lane = tid & 63, quad = lane >> 4, ln = lane & 15;
    const int rl = lane >> 3, sl = lane & 7, jgz = sl ^ rl;
    const int w8 = w * 8;
    const int grow = w8 + rl;
    const unsigned short* qrow_p = qkv + ((size_t)(b * T) + grow) * QS2 + hh * 64 + jgz * 8;
    const unsigned short* krow_p = qrow_p + 512;
    const unsigned short* vrow_p = vt + ((size_t)(bh * 64) + grow) * T + jgz * 8;

    glds16(qrow_p + (size_t)(qtA * 64) * QS2, QA + w8 * 64);
    glds16(qrow_p + (size_t)(qtA * 64 + 32) * QS2, QA + (w8 + 32) * 64);
    glds16(qrow_p + (size_t)(qtB * 64) * QS2, QB + w8 * 64);
    glds16(qrow_p + (size_t)(qtB * 64 + 32) * QS2, QB + (w8 + 32) * 64);

    fvec4 oA[4], oB[4], lAv, lBv;
#pragma unroll
    for (int r = 0; r < 4; r++) { lAv[r] = 0.f; lBv[r] = 0.f; }
#pragma unroll
    for (int nt = 0; nt < 4; nt++)
#pragma unroll
        for (int r = 0; r < 4; r++) { oA[nt][r] = 0.f; oB[nt][r] = 0.f; }

    const int Nph = (nst + 1) >> 1;
    for (int ph = 0; ph < Nph; ph++) {
        const int s0 = 2 * ph, s1 = 2 * ph + 1;
        __syncthreads();   // all reads of K0/V0/K1/V1 from previous phase complete
        glds16(krow_p + (size_t)(s0 * 64) * QS2, K0 + w8 * 64);
        glds16(krow_p + (size_t)(s0 * 64 + 32) * QS2, K0 + (w8 + 32) * 64);
        glds16(vrow_p + s0 * 64, V0 + w8 * 64);
        glds16(vrow_p + (size_t)32 * T + s0 * 64, V0 + (w8 + 32) * 64);
        if (s1 < nst) {
            glds16(krow_p + (size_t)(s1 * 64) * QS2, K1 + w8 * 64);
            glds16(krow_p + (size_t)(s1 * 64 + 32) * QS2, K1 + (w8 + 32) * 64);
            glds16(vrow_p + s1 * 64, V1 + w8 * 64);
            glds16(vrow_p + (size_t)32 * T + s1 * 64, V1 + (w8 + 32) * 64);
        }
        __syncthreads();   // vmcnt drained: staged data visible
        if (s0 == nst - 1) attn_step<true >(QB, Ps, K0, V0, oB, lBv, w, quad, ln);
        else               attn_step<false>(QB, Ps, K0, V0, oB, lBv, w, quad, ln);
        if (s0 <= p) {
            if (s0 == p) attn_step<true >(QA, Ps, K0, V0, oA, lAv, w, quad, ln);
            else         attn_step<false>(QA, Ps, K0, V0, oA, lAv, w, quad, ln);
        }
        if (s1 < nst) {
            if (s1 == nst - 1) attn_step<true >(QB, Ps, K1, V1, oB, lBv, w, quad, ln);
            else               attn_step<false>(QB, Ps, K1, V1, oB, lBv, w, quad, ln);
            if (s1 <= p) {
                if (s1 == p) attn_step<true >(QA, Ps, K1, V1, oA, lAv, w, quad, ln);
                else         attn_step<false>(QA, Ps, K1, V1, oA, lAv, w, quad, ln);
            }
        }
    }

    unsigned short* ogA = o + (size_t)(b * T + qtA * 64 + w * 16 + quad * 4) * D + hh * 64;
    unsigned short* ogB = o + (size_t)(b * T + qtB * 64 + w * 16 + quad * 4) * D + hh * 64;
#pragma unroll
    for (int r = 0; r < 4; r++) {
        float ia = 1.f / lAv[r], ib = 1.f / lBv[r];
#pragma unroll
        for (int nt = 0; nt < 4; nt++) {
            ogA[(size_t)r * D + nt * 16 + ln] = f2b(oA[nt][r] * ia);
            ogB[(size_t)r * D + nt * 16 + ln] = f2b(oB[nt][r] * ib);
        }
    }
}

// ---------------- masked-mean pool partials ----------------
__global__ __launch_bounds__(256)
void pool_kernel(const float* __restrict__ hn, const float* __restrict__ x, float* __restrict__ part)
{
    int b = blockIdx.x, ch = blockIdx.y, tid = threadIdx.x;
    int t0 = ch * 128;
    float s0 = 0.f, s1 = 0.f, cnt = 0.f;
    for (int tt = 0; tt < 128; tt++) {
        int t = t0 + tt;
        float xv = x[b * T + t];
        float m = (xv == -1.0f) ? 0.f : 1.f;
        cnt += m;
        const float* r = hn + ((size_t)(b * T + t)) * D;
        s0 += r[tid] * m;
        s1 += r[tid + 256] * m;
    }
    float* pr = part + (size_t)(b * 16 + ch) * 513;
    pr[tid] = s0; pr[tid + 256] = s1;
    if (tid == 0) pr[512] = cnt;
}

// ---------------- heads ----------------
__global__ __launch_bounds__(64)
void head_kernel(const float* __restrict__ part,
                 const float* __restrict__ bh_g, const float* __restrict__ bh_bl,
                 const float* __restrict__ ah_g, const float* __restrict__ ah_bl,
                 const float* __restrict__ ch_g, const float* __restrict__ ch_bl,
                 const float* __restrict__ bh_w, const float* __restrict__ bh_b2,
                 const float* __restrict__ ah_w, const float* __restrict__ ah_b2,
                 const float* __restrict__ ch_w, const float* __restrict__ ch_b2,
                 float* __restrict__ out)
{
    int b = blockIdx.x, lane = threadIdx.x;
    float cnt = 0.f;
    for (int c = 0; c < 16; c++) cnt += part[(size_t)(b * 16 + c) * 513 + 512];
    float denom = fmaxf(cnt, 1.f);
    float md[8];
    float s = 0.f, s2 = 0.f;
#pragma unroll
    for (int j = 0; j < 8; j++) {
        int d = j * 64 + lane;
        float acc = 0.f;
        for (int c = 0; c < 16; c++) acc += part[(size_t)(b * 16 + c) * 513 + d];
        md[j] = acc / denom;
        s += md[j]; s2 += md[j] * md[j];
    }
    s = wave_red_sum(s); s2 = wave_red_sum(s2);
    float mu = s * (1.f / 512.f);
    float var = s2 * (1.f / 512.f) - mu * mu;
    float rstd = 1.f / sqrtf(var + 1e-5f);
    float a0 = 0.f, a1 = 0.f, a2 = 0.f, a3 = 0.f;
#pragma unroll
    for (int j = 0; j < 8; j++) {
        int d = j * 64 + lane;
        float z = (md[j] - mu) * rstd;
        float zb = z * bh_g[d] + bh_bl[d];
        a0 += zb * bh_w[d * 2 + 0];
        a1 += zb * bh_w[d * 2 + 1];
        a2 += (z * ah_g[d] + ah_bl[d]) * ah_w[d];
        a3 += (z * ch_g[d] + ch_bl[d]) * ch_w[d];
    }
    a0 = wave_red_sum(a0); a1 = wave_red_sum(a1);
    a2 = wave_red_sum(a2); a3 = wave_red_sum(a3);
    if (lane == 0) {
        out[b * 4 + 0] = a0 + bh_b2[0];
        out[b * 4 + 1] = a1 + bh_b2[1];
        out[b * 4 + 2] = a2 + ah_b2[0];
        float t3 = a3 + ch_b2[0];
        out[b * 4 + 3] = 1.f / (1.f + expf(-t3));
    }
}

// ---------------- launch ----------------
extern "C" void kernel_launch(void* const* d_in, const int* in_sizes, int n_in,
                              void* d_out, int out_size, void* d_ws, size_t ws_size,
                              hipStream_t stream)
{
    const float* x      = (const float*)d_in[0];
    const float* ip_w   = (const float*)d_in[1];
    const float* ip_b   = (const float*)d_in[2];
    const float* ip_ln_g= (const float*)d_in[3];
    const float* ip_ln_b= (const float*)d_in[4];
    const float* pos    = (const float*)d_in[5];
    const float* pad_tok= (const float*)d_in[6];
    const float* Wq = (const float*)d_in[7];  const float* bq = (const float*)d_in[8];
    const float* Wk = (const float*)d_in[9];  const float* bk = (const float*)d_in[10];
    const float* Wv = (const float*)d_in[11]; const float* bv = (const float*)d_in[12];
    const float* Wo = (const float*)d_in[13]; const float* bo = (const float*)d_in[14];
    const float* ln1_g = (const float*)d_in[15]; const float* ln1_b = (const float*)d_in[16];
    const float* ln2_g = (const float*)d_in[17]; const float* ln2_b = (const float*)d_in[18];
    const float* W1 = (const float*)d_in[19]; const float* b1 = (const float*)d_in[20];
    const float* W2 = (const float*)d_in[21]; const float* b2 = (const float*)d_in[22];
    const float* gate1 = (const float*)d_in[23]; const float* gate2 = (const float*)d_in[24];
    const float* fn_g = (const float*)d_in[25]; const float* fn_b = (const float*)d_in[26];
    const float* bh_g  = (const float*)d_in[27]; const float* bh_bl = (const float*)d_in[28];
    const float* ah_g  = (const float*)d_in[29]; const float* ah_bl = (const float*)d_in[30];
    const float* ch_g  = (const float*)d_in[31]; const float* ch_bl = (const float*)d_in[32];
    const float* bh_w  = (const float*)d_in[33]; const float* bh_b2 = (const float*)d_in[34];
    const float* ah_w  = (const float*)d_in[35]; const float* ah_b2 = (const float*)d_in[36];
    const float* ch_w  = (const float*)d_in[37]; const float* ch_b2 = (const float*)d_in[38];

    char* ws = (char*)d_ws;
    float*          h     = (float*)ws;                       // 16 MB fp32 [8192][512]
    unsigned short* act_b = (unsigned short*)(ws + 16777216); // 8 MB bf16 [8192][512]
    unsigned short* qkv   = (unsigned short*)(ws + 25165824); // 16 MB bf16 [8192][1024] (q|k)
    unsigned short* mid_b = (unsigned short*)(ws + 41943040); // 32 MB bf16 [8192][2048]
    float*          xn_f  = (float*)(ws + 41943040);          // 16 MB alias (final LN only)
    unsigned short* wT    = (unsigned short*)(ws + 75497472); // 6 MB per-layer transposed weights
    unsigned short* vt    = (unsigned short*)(ws + 81788928); // 8 MB bf16 [4*512][2048]
    float*          part  = (float*)(ws + 90177536);
    float*          out   = (float*)d_out;

    unsigned short* wqT = wT;             // [1536][512] (q,k,v contiguous)
    unsigned short* wkT = wT + 262144;
    unsigned short* wvT = wT + 524288;
    unsigned short* woT = wT + 786432;
    unsigned short* w1T = wT + 1048576;   // [2048][512]
    unsigned short* w2T = wT + 2097152;   // [512][2048]

    embed_kernel<<<dim3(Bsz * T), dim3(64), 0, stream>>>(x, ip_w, ip_b, ip_ln_g, ip_ln_b, pos, pad_tok, h);

    for (int i = 0; i < Lnum; i++) {
        const size_t dd = (size_t)i * D * D;
        const size_t df = (size_t)i * D * DFF;
        wconv_kernel<<<dim3(3072), dim3(256), 0, stream>>>(Wq + dd, Wk + dd, Wv + dd, Wo + dd,
                                                           W1 + df, W2 + df,
                                                           wqT, wkT, wvT, woT, w1T, w2T);
        ln_bf16_kernel<<<dim3(Bsz * T / 4), dim3(256), 0, stream>>>(h, act_b, ln1_g + i * D, ln1_b + i * D);
        gemm_bf16<0, 1, 128><<<dim3(64, 12), dim3(256), 0, stream>>>(act_b, wqT, bq + i * D, bk + i * D, bv + i * D,
                                                                     nullptr, qkv, vt, Bsz * T, 1536, D, nullptr);
        attn_pair_kernel<<<dim3(512), dim3(256), 0, stream>>>(qkv, vt, act_b);
        gemm_bf16<1, 0, 64><<<dim3(128, 4), dim3(256), 0, stream>>>(act_b, woT, bo + i * D, nullptr, nullptr,
                                                                    h, h, nullptr, Bsz * T, D, D, gate1 + i);
        ln_bf16_kernel<<<dim3(Bsz * T / 4), dim3(256), 0, stream>>>(h, act_b, ln2_g + i * D, ln2_b + i * D);
        gemm_bf16<2, 1, 128><<<dim3(64, 16), dim3(256), 0, stream>>>(act_b, w1T, b1 + i * DFF, nullptr, nullptr,
                                                                     nullptr, mid_b, nullptr, Bsz * T, DFF, D, nullptr);
        gemm_bf16<3, 0, 64><<<dim3(128, 4), dim3(256), 0, stream>>>(mid_b, w2T, b2 + i * D, nullptr, nullptr,
                                                                    h, h, nullptr, Bsz * T, D, DFF, gate2 + i);
    }

    ln_kernel<<<dim3(Bsz * T / 4), dim3(256), 0, stream>>>(h, xn_f, fn_g, fn_b);
    pool_kernel<<<dim3(Bsz, 16), dim3(256), 0, stream>>>(xn_f, x, part);
    head_kernel<<<dim3(Bsz), dim3(64), 0, stream>>>(part, bh_g, bh_bl, ah_g, ah_bl, ch_g, ch_bl,
                                                    bh_w, bh_b2, ah_w, ah_b2, ch_w, ch_b2, out);
}